// Round 8
// baseline (527.834 us; speedup 1.0000x reference)
//
#include <hip/hip_runtime.h>
#include <cstdint>

// Problem constants
#define BB 4
#define LL 1024
#define DM 512
#define DI 1024
#define DS 16
#define DTR 32
#define NX 64          // DTR + 2*DS
#define MROWS 4096     // B*L
#define CH 32          // scan chunk length
#define NCH 32         // LL / CH

typedef unsigned short u16;
typedef __attribute__((ext_vector_type(8))) short bf16x8;
typedef __attribute__((ext_vector_type(4))) float f32x4;

__device__ __forceinline__ float bf2f(u16 u) {
    union { unsigned int i; float f; } v;
    v.i = ((unsigned int)u) << 16;
    return v.f;
}
__device__ __forceinline__ u16 f2bf(float f) {
    union { float f; unsigned u; } v;
    v.f = f;
    return (u16)((v.u + 0x7fffu + ((v.u >> 16) & 1u)) >> 16);
}

// ---------------------------------------------------------------------------
// Weight transpose+cast: src[K][N] f32 -> dst[N][K] bf16. z = layer*4 + which.
__global__ __launch_bounds__(256) void wtrans(
    const float* __restrict__ Wi, const float* __restrict__ Wo,
    const float* __restrict__ Wx, const float* __restrict__ Wdt,
    u16* __restrict__ WiT, u16* __restrict__ WoT,
    u16* __restrict__ WxT, u16* __restrict__ WdtT)
{
    int l = blockIdx.z >> 2, w = blockIdx.z & 3;
    int K, N; const float* src; u16* dst;
    if (w == 0)      { K = 512;  N = 2048; src = Wi + (size_t)l * 512 * 2048;  dst = WiT + (size_t)l * 2048 * 512; }
    else if (w == 1) { K = 1024; N = 512;  src = Wo + (size_t)l * 1024 * 512;  dst = WoT + (size_t)l * 512 * 1024; }
    else if (w == 2) { K = 1024; N = 64;   src = Wx + (size_t)l * 1024 * 64;   dst = WxT + (size_t)l * 64 * 1024; }
    else             { K = 32;   N = 1024; src = Wdt + (size_t)l * 32 * 1024;  dst = WdtT + (size_t)l * 1024 * 32; }
    int n0 = blockIdx.x * 64, k0 = blockIdx.y * 64;
    if (n0 >= N || k0 >= K) return;
    __shared__ u16 tile[64][65];
    int tn = threadIdx.x & 63, tr = threadIdx.x >> 6;
    for (int r = tr; r < 64; r += 4) {
        int k = k0 + r;
        if (k < K && n0 + tn < N)
            tile[r][tn] = f2bf(src[(size_t)k * N + n0 + tn]);
    }
    __syncthreads();
    for (int r = tr; r < 64; r += 4) {
        int n = n0 + r, k = k0 + tn;
        if (n < N && k < K)
            dst[(size_t)n * K + k] = tile[tn][r];
    }
}

// ---------------------------------------------------------------------------
// cast f32 -> bf16 (x input)
__global__ void cast_bf16(const float4* __restrict__ in, ushort4* __restrict__ out, int n4) {
    int i = blockIdx.x * 256 + threadIdx.x;
    if (i < n4) {
        float4 v = in[i];
        out[i] = make_ushort4(f2bf(v.x), f2bf(v.y), f2bf(v.z), f2bf(v.w));
    }
}

// ---------------------------------------------------------------------------
// Software-pipelined MFMA bf16 GEMM with LDS-staged wide-store epilogue.
// A[M][lda] bf16, W[N][ldb] bf16 (pre-transposed), C typed CT (float or u16).
// Tile TM x TN, 4 waves (2x2), BK=32, XOR-swizzled LDS. Register prefetch of
// next k-iter. SP: softplus(acc+bias) epilogue. XS: XCD-aware swizzle for the
// in_proj 32x32 grid (1-D launch). Split-K via blockIdx.z.
template <int TM, int TN, int SP, int XS, typename CT>
__global__ __launch_bounds__(256) void gemm_pipe(
    const u16* __restrict__ A, const u16* __restrict__ W, CT* __restrict__ C,
    int lda, int ldb, int ldc, int kchunk, const float* __restrict__ bias)
{
    constexpr int NI = TM / 32, NJ = TN / 32;
    constexpr int SLOTS = (TM + TN) * 4 / 256;
    constexpr int CSTRIDE = TN * (int)sizeof(CT) + 16;   // padded bytes/row
    constexpr int CBYTES = 32 * CSTRIDE;
    constexpr int LBYTES = ((TM + TN) * 64 > CBYTES) ? (TM + TN) * 64 : CBYTES;
    __shared__ char lds[LBYTES];
    const int tid = threadIdx.x;
    const int lane = tid & 63;
    const int wave = tid >> 6;
    const int wm = wave >> 1, wn = wave & 1;
    const int lm = lane & 15, quad = lane >> 4;

    int bx, by;
    if (XS) {   // 32x32 grid: XCD (bid&7) owns a 8-rowtile x 16-coltile patch
        int bid = blockIdx.x;
        int xcd = bid & 7, idx = bid >> 3;
        by = (xcd & 3) * 8 + (idx & 7);
        bx = (xcd >> 2) * 16 + (idx >> 3);
    } else { bx = blockIdx.x; by = blockIdx.y; }
    const int row0 = by * TM, col0 = bx * TN;
    const int kstart = blockIdx.z * kchunk;
    CT* Cz = C + (size_t)blockIdx.z * (size_t)(gridDim.y * TM) * ldc;

    const u16* sp[SLOTS];
    int lo[SLOTS];
#pragma unroll
    for (int s = 0; s < SLOTS; ++s) {
        int slot = s * 256 + tid;
        int row = slot >> 2, g = slot & 3;
        if (row < TM) sp[s] = A + (size_t)(row0 + row) * lda + kstart + g * 8;
        else          sp[s] = W + (size_t)(col0 + row - TM) * ldb + kstart + g * 8;
        lo[s] = row * 64 + ((g ^ (row & 3)) << 4);
    }

    f32x4 acc[NI][NJ];
#pragma unroll
    for (int i = 0; i < NI; ++i)
#pragma unroll
        for (int j = 0; j < NJ; ++j) acc[i][j] = (f32x4){0.f, 0.f, 0.f, 0.f};

    uint4 v[SLOTS];
#pragma unroll
    for (int s = 0; s < SLOTS; ++s) {
        v[s] = *(const uint4*)sp[s];
        sp[s] += 32;
    }

    for (int k0 = 0; k0 < kchunk; k0 += 32) {
        __syncthreads();
#pragma unroll
        for (int s = 0; s < SLOTS; ++s)
            *(uint4*)(lds + lo[s]) = v[s];
        if (k0 + 32 < kchunk) {
#pragma unroll
            for (int s = 0; s < SLOTS; ++s) {
                v[s] = *(const uint4*)sp[s];   // in flight through MFMA stage
                sp[s] += 32;
            }
        }
        __syncthreads();

        bf16x8 af[NI], bf[NJ];
#pragma unroll
        for (int i = 0; i < NI; ++i) {
            int r = wm * (TM / 2) + i * 16 + lm;
            af[i] = *(const bf16x8*)(lds + r * 64 + ((quad ^ (lm & 3)) << 4));
        }
#pragma unroll
        for (int j = 0; j < NJ; ++j) {
            int r = TM + wn * (TN / 2) + j * 16 + lm;
            bf[j] = *(const bf16x8*)(lds + r * 64 + ((quad ^ (lm & 3)) << 4));
        }
#pragma unroll
        for (int i = 0; i < NI; ++i)
#pragma unroll
            for (int j = 0; j < NJ; ++j)
                acc[i][j] = __builtin_amdgcn_mfma_f32_16x16x32_bf16(
                    af[i], bf[j], acc[i][j], 0, 0, 0);
    }

    // ---- epilogue: stage 32 x TN C-rows in LDS, store wide & contiguous ----
#pragma unroll
    for (int i = 0; i < NI; ++i) {
        __syncthreads();    // LDS free (frag reads of last k-iter done / prev i stores done)
#pragma unroll
        for (int j = 0; j < NJ; ++j) {
#pragma unroll
            for (int r = 0; r < 4; ++r) {
                int lr = wm * 16 + quad * 4 + r;           // 0..31
                int lc = wn * (TN / 2) + j * 16 + lm;      // 0..TN-1
                float val = acc[i][j][r];
                if (SP) {
                    val += bias[col0 + lc];
                    val = fmaxf(val, 0.f) + log1pf(__expf(-fabsf(val)));
                }
                if (sizeof(CT) == 2)
                    *(u16*)(lds + lr * CSTRIDE + lc * 2) = f2bf(val);
                else
                    *(float*)(lds + lr * CSTRIDE + lc * 4) = val;
            }
        }
        __syncthreads();
        constexpr int TPR = TN * (int)sizeof(CT) / 16;     // 16B segments/row
        int seg = tid % TPR;
        for (int rr = tid / TPR; rr < 32; rr += 256 / TPR) {
            int gr = row0 + (rr >> 4) * (TM / 2) + i * 16 + (rr & 15);
            *(uint4*)((char*)(Cz + (size_t)gr * ldc + col0) + seg * 16) =
                *(const uint4*)(lds + rr * CSTRIDE + seg * 16);
        }
    }
}

// ---------------------------------------------------------------------------
// reduce split-K partials: dbc = sum_z pxp[z]; also emit bf16 copy for dt_proj
__global__ __launch_bounds__(256) void reduce_dbc(
    const float4* __restrict__ px, float4* __restrict__ dbc, ushort4* __restrict__ dbcb)
{
    int i = blockIdx.x * 256 + threadIdx.x;   // 65536 float4s
    float4 s = px[i];
#pragma unroll
    for (int z = 1; z < 8; ++z) {
        float4 v = px[(size_t)z * 65536 + i];
        s.x += v.x; s.y += v.y; s.z += v.z; s.w += v.w;
    }
    dbc[i] = s;
    dbcb[i] = make_ushort4(f2bf(s.x), f2bf(s.y), f2bf(s.z), f2bf(s.w));
}

// ---------------------------------------------------------------------------
// depthwise causal conv (kernel 4) + bias + SiLU; bf16 in (xz), bf16 out (xs)
__global__ void conv_silu_kernel(const u16* __restrict__ xz,
                                 const float* __restrict__ cw, const float* __restrict__ cb,
                                 ushort4* __restrict__ xs)
{
    int i = blockIdx.x * 256 + threadIdx.x;   // 0 .. 1M-1 (d-quads)
    int d = (i & 255) * 4;
    int bt = i >> 8;
    int t = bt & (LL - 1);
    float a0 = cb[d], a1 = cb[d + 1], a2 = cb[d + 2], a3 = cb[d + 3];
    float4 w0 = *(const float4*)(cw + (size_t)d * 4);
    float4 w1 = *(const float4*)(cw + (size_t)(d + 1) * 4);
    float4 w2 = *(const float4*)(cw + (size_t)(d + 2) * 4);
    float4 w3 = *(const float4*)(cw + (size_t)(d + 3) * 4);
    const float* wp0 = (const float*)&w0;
    const float* wp1 = (const float*)&w1;
    const float* wp2 = (const float*)&w2;
    const float* wp3 = (const float*)&w3;
#pragma unroll
    for (int k = 0; k < 4; ++k) {
        int tt = t - 3 + k;
        if (tt >= 0) {
            ushort4 xv = *(const ushort4*)(xz + (size_t)(bt - 3 + k) * 2048 + d);
            a0 = fmaf(bf2f(xv.x), wp0[k], a0);
            a1 = fmaf(bf2f(xv.y), wp1[k], a1);
            a2 = fmaf(bf2f(xv.z), wp2[k], a2);
            a3 = fmaf(bf2f(xv.w), wp3[k], a3);
        }
    }
    xs[i] = make_ushort4(
        f2bf(a0 / (1.f + __expf(-a0))), f2bf(a1 / (1.f + __expf(-a1))),
        f2bf(a2 / (1.f + __expf(-a2))), f2bf(a3 / (1.f + __expf(-a3))));
}

// ---------------------------------------------------------------------------
// Chunk-parallel scan, register-state (one thread = all 16 states of (b,chunk,d))
__global__ __launch_bounds__(256) void scan_pass1(
    const u16* __restrict__ delta, const u16* __restrict__ xs,
    const float* __restrict__ dbc, const float* __restrict__ A_log,
    float* __restrict__ P, float* __restrict__ Q)
{
    const int dgrp = blockIdx.x & 3;
    const int chunk = (blockIdx.x >> 2) & (NCH - 1);
    const int b = blockIdx.x >> 7;
    const int d = dgrp * 256 + threadIdx.x;
    const int t0 = b * LL + chunk * CH;

    __shared__ float sB[CH][DS];
    {
        int i = threadIdx.x;
        int row = i >> 3, col = (i & 7) * 2;
        float2 v = *(const float2*)(dbc + (size_t)(t0 + row) * NX + DTR + col);
        sB[row][col] = v.x; sB[row][col + 1] = v.y;
    }
    float An[DS];
#pragma unroll
    for (int n = 0; n < DS; ++n) An[n] = -__expf(A_log[d * DS + n]);
    __syncthreads();

    float Pv[DS], h[DS];
#pragma unroll
    for (int n = 0; n < DS; ++n) { Pv[n] = 1.f; h[n] = 0.f; }

    const u16* dp = delta + (size_t)t0 * DI + d;
    const u16* xp = xs + (size_t)t0 * DI + d;
#pragma unroll 4
    for (int t = 0; t < CH; ++t) {
        float dlt = bf2f(dp[t * DI]);
        float du = dlt * bf2f(xp[t * DI]);
#pragma unroll
        for (int n = 0; n < DS; ++n) {
            float dA = __expf(dlt * An[n]);
            Pv[n] *= dA;
            h[n] = fmaf(dA, h[n], du * sB[t][n]);
        }
    }
    size_t base = ((size_t)(b * NCH + chunk) * DI + d) * DS;
    float4* Pp = (float4*)(P + base);
    float4* Qp = (float4*)(Q + base);
#pragma unroll
    for (int g = 0; g < 4; ++g) {
        Pp[g] = make_float4(Pv[g * 4], Pv[g * 4 + 1], Pv[g * 4 + 2], Pv[g * 4 + 3]);
        Qp[g] = make_float4(h[g * 4], h[g * 4 + 1], h[g * 4 + 2], h[g * 4 + 3]);
    }
}

__global__ __launch_bounds__(256) void scan_pass2(float* __restrict__ P,
                                                  const float* __restrict__ Q)
{
    int tid = blockIdx.x * 256 + threadIdx.x;
    int n = tid & 15;
    int d = (tid >> 4) & (DI - 1);
    int b = tid >> 14;
    float carry = 0.f;
    for (int c = 0; c < NCH; ++c) {
        size_t i = ((size_t)(b * NCH + c) * DI + d) * DS + n;
        float Pv = P[i], Qv = Q[i];
        P[i] = carry;
        carry = fmaf(Pv, carry, Qv);
    }
}

// pass3: re-run from H_in; y = sum_n h_n C_n + D-skip, silu(z) gate -> y bf16
__global__ __launch_bounds__(256) void scan_pass3(
    const u16* __restrict__ delta, const u16* __restrict__ xs,
    const float* __restrict__ dbc, const u16* __restrict__ xz,
    const float* __restrict__ A_log, const float* __restrict__ Dsk,
    const float* __restrict__ Hin, u16* __restrict__ yb)
{
    const int dgrp = blockIdx.x & 3;
    const int chunk = (blockIdx.x >> 2) & (NCH - 1);
    const int b = blockIdx.x >> 7;
    const int d = dgrp * 256 + threadIdx.x;
    const int t0 = b * LL + chunk * CH;

    __shared__ float sBC[CH][32];   // cols 0..15 = B, 16..31 = C
    {
        int i = threadIdx.x;
        int row = i >> 3, col = (i & 7) * 4;
        float4 v = *(const float4*)(dbc + (size_t)(t0 + row) * NX + DTR + col);
        *(float4*)&sBC[row][col] = v;
    }
    float An[DS];
#pragma unroll
    for (int n = 0; n < DS; ++n) An[n] = -__expf(A_log[d * DS + n]);
    const float Dd = Dsk[d];

    float h[DS];
    {
        size_t base = ((size_t)(b * NCH + chunk) * DI + d) * DS;
        const float4* Hp = (const float4*)(Hin + base);
#pragma unroll
        for (int g = 0; g < 4; ++g) {
            float4 v = Hp[g];
            h[g * 4] = v.x; h[g * 4 + 1] = v.y; h[g * 4 + 2] = v.z; h[g * 4 + 3] = v.w;
        }
    }
    __syncthreads();

    const u16* dp = delta + (size_t)t0 * DI + d;
    const u16* xp = xs + (size_t)t0 * DI + d;
    const u16* zp = xz + (size_t)t0 * 2048 + DI + d;
    u16* yp = yb + (size_t)t0 * DI + d;

#pragma unroll 4
    for (int t = 0; t < CH; ++t) {
        float dlt = bf2f(dp[t * DI]);
        float xv  = bf2f(xp[t * DI]);
        float zv  = bf2f(zp[t * 2048]);
        float du = dlt * xv;
        float y = 0.f;
#pragma unroll
        for (int n = 0; n < DS; ++n) {
            float dA = __expf(dlt * An[n]);
            h[n] = fmaf(dA, h[n], du * sBC[t][n]);
            y = fmaf(h[n], sBC[t][DS + n], y);
        }
        y += xv * Dd;
        float sz = zv / (1.f + __expf(-zv));
        yp[t * DI] = f2bf(y * sz);
    }
}

// ---------------------------------------------------------------------------
// residual add + LayerNorm; writes f32 hout; optionally bf16 copy (next GEMM A)
__global__ __launch_bounds__(512) void ln_kernel(
    const float* __restrict__ o, const float* __restrict__ hprev,
    const float* __restrict__ g, const float* __restrict__ bta,
    float* __restrict__ hout, u16* __restrict__ hbf, int wb)
{
    int row = blockIdx.x, c = threadIdx.x;
    size_t off = (size_t)row * DM + c;
    float v = o[off] + hprev[off];
    float s1 = v, s2 = v * v;
#pragma unroll
    for (int m = 32; m >= 1; m >>= 1) {
        s1 += __shfl_xor(s1, m);
        s2 += __shfl_xor(s2, m);
    }
    __shared__ float r1[8], r2[8];
    __shared__ float stats[2];
    int w = c >> 6;
    if ((c & 63) == 0) { r1[w] = s1; r2[w] = s2; }
    __syncthreads();
    if (c == 0) {
        float a = 0.f, q = 0.f;
        for (int i = 0; i < 8; ++i) { a += r1[i]; q += r2[i]; }
        float mean = a / (float)DM;
        float var = q / (float)DM - mean * mean;
        stats[0] = mean;
        stats[1] = rsqrtf(var + 1e-5f);
    }
    __syncthreads();
    float res = (v - stats[0]) * stats[1] * g[c] + bta[c];
    hout[off] = res;
    if (wb) hbf[off] = f2bf(res);
}

// ---------------------------------------------------------------------------
extern "C" void kernel_launch(void* const* d_in, const int* in_sizes, int n_in,
                              void* d_out, int out_size, void* d_ws, size_t ws_size,
                              hipStream_t stream)
{
    const float* x    = (const float*)d_in[0];
    const float* Wi   = (const float*)d_in[1];
    const float* cw   = (const float*)d_in[2];
    const float* cb   = (const float*)d_in[3];
    const float* Wx   = (const float*)d_in[4];
    const float* Wdt  = (const float*)d_in[5];
    const float* bdt  = (const float*)d_in[6];
    const float* Alog = (const float*)d_in[7];
    const float* Dsk  = (const float*)d_in[8];
    const float* Wo   = (const float*)d_in[9];
    const float* lng  = (const float*)d_in[10];
    const float* lnb  = (const float*)d_in[11];

    // workspace (ws_size = 268 MB; using ~88 MB)
    float* fw   = (float*)d_ws;
    float* h    = fw;                      // 2M f32
    float* ob   = h + 2097152;             // 2M f32
    float* dbc  = ob + 2097152;            // 256K f32
    float* pxp  = dbc + 262144;            // 2M f32 (8 x 4096 x 64)
    float* Pb   = pxp + 2097152;           // 2M f32
    float* Qb   = Pb + 2097152;            // 2M f32
    u16* xzb    = (u16*)(Qb + 2097152);    // 8M u16 (4096 x 2048)
    u16* xsbf   = xzb + 8388608;           // 4M u16
    u16* abf    = xsbf + 4194304;          // 4M u16 (x/h bf16, then y bf16)
    u16* dltb   = abf + 4194304;           // 4M u16
    u16* dbcb   = dltb + 4194304;          // 256K u16
    u16* WiT    = dbcb + 262144;           // 2 x 1M u16
    u16* WoT    = WiT + 2097152;           // 2 x 512K u16
    u16* WxT    = WoT + 1048576;           // 2 x 64K u16
    u16* WdtT   = WxT + 131072;            // 2 x 32K u16

    // one-time per call: x -> bf16, all weights -> [N][K] bf16
    cast_bf16<<<2048, 256, 0, stream>>>((const float4*)x, (ushort4*)abf, 524288);
    wtrans<<<dim3(32, 16, 8), 256, 0, stream>>>(Wi, Wo, Wx, Wdt, WiT, WoT, WxT, WdtT);

    for (int l = 0; l < 2; ++l) {
        const float* hin = (l == 0) ? x : h;
        const u16* WiTl  = WiT  + (size_t)l * 2048 * 512;
        const u16* WoTl  = WoT  + (size_t)l * 512 * 1024;
        const u16* WxTl  = WxT  + (size_t)l * 64 * 1024;
        const u16* WdtTl = WdtT + (size_t)l * 1024 * 32;

        // xz = h @ Wi  (4096 x 2048, K=512) -> bf16, XCD-swizzled 1-D grid
        gemm_pipe<128, 64, 0, 1, u16><<<1024, 256, 0, stream>>>(
            abf, WiTl, xzb, 512, 512, 2048, 512, nullptr);

        // xs = silu(conv(xin) + cb) -> bf16
        conv_silu_kernel<<<4096, 256, 0, stream>>>(
            xzb, cw + (size_t)l * DI * 4, cb + (size_t)l * DI, (ushort4*)xsbf);

        // dbc partials = xs @ Wx  (split-K=8, deterministic) -> f32
        gemm_pipe<128, 64, 0, 0, float><<<dim3(1, 32, 8), 256, 0, stream>>>(
            xsbf, WxTl, pxp, 1024, 1024, 64, 128, nullptr);
        reduce_dbc<<<256, 256, 0, stream>>>(
            (const float4*)pxp, (float4*)dbc, (ushort4*)dbcb);

        // delta = softplus(dbc[:, :32] @ Wdt + bdt)  (K=32) -> bf16
        gemm_pipe<128, 64, 1, 0, u16><<<dim3(16, 32, 1), 256, 0, stream>>>(
            dbcb, WdtTl, dltb, 64, 32, 1024, 32, bdt + (size_t)l * DI);

        // chunk-parallel selective scan -> y bf16 (into abf)
        scan_pass1<<<BB * NCH * 4, 256, 0, stream>>>(
            dltb, xsbf, dbc, Alog + (size_t)l * DI * DS, Pb, Qb);
        scan_pass2<<<256, 256, 0, stream>>>(Pb, Qb);
        scan_pass3<<<BB * NCH * 4, 256, 0, stream>>>(
            dltb, xsbf, dbc, xzb, Alog + (size_t)l * DI * DS, Dsk + (size_t)l * DI,
            Pb, abf);

        // o = y @ Wo  (4096 x 512, K=1024) -> f32
        gemm_pipe<64, 64, 0, 0, float><<<dim3(8, 64, 1), 256, 0, stream>>>(
            abf, WoTl, ob, 1024, 1024, 512, 1024, nullptr);

        // h = LN(o + hin); l=0 also writes bf16 h into abf; l=1 -> d_out
        ln_kernel<<<MROWS, 512, 0, stream>>>(
            ob, hin, lng + (size_t)l * DM, lnb + (size_t)l * DM,
            (l == 1) ? (float*)d_out : h, abf, l == 0);
    }
}

// Round 9
// 414.146 us; speedup vs baseline: 1.2745x; 1.2745x over previous
//
#include <hip/hip_runtime.h>
#include <cstdint>

// Problem constants
#define BB 4
#define LL 1024
#define DM 512
#define DI 1024
#define DS 16
#define DTR 32
#define NX 64          // DTR + 2*DS
#define MROWS 4096     // B*L
#define CH 32          // scan chunk length
#define NCH 32         // LL / CH

typedef unsigned short u16;
typedef __attribute__((ext_vector_type(8))) short bf16x8;
typedef __attribute__((ext_vector_type(4))) float f32x4;

#if defined(__has_builtin)
#if __has_builtin(__builtin_amdgcn_global_load_lds)
#define HAS_ASYNC 1
#endif
#endif
#ifndef HAS_ASYNC
#define HAS_ASYNC 0
#endif

__device__ __forceinline__ float bf2f(u16 u) {
    union { unsigned int i; float f; } v;
    v.i = ((unsigned int)u) << 16;
    return v.f;
}
__device__ __forceinline__ u16 f2bf(float f) {
    union { float f; unsigned u; } v;
    v.f = f;
    return (u16)((v.u + 0x7fffu + ((v.u >> 16) & 1u)) >> 16);
}
__device__ __forceinline__ unsigned pack_bf16(float a, float b) {
    union { float f; unsigned u; } ua, ub;
    ua.f = a; ub.f = b;
    unsigned ra = (ua.u + 0x7fffu + ((ua.u >> 16) & 1u)) >> 16;
    unsigned rb = (ub.u + 0x7fffu + ((ub.u >> 16) & 1u)) & 0xffff0000u;
    return ra | rb;
}

#if HAS_ASYNC
// async global -> LDS, 16 B per lane. LDS dest = wave-uniform base + lane*16.
__device__ __forceinline__ void gld_lds16(const void* g, void* l) {
    __builtin_amdgcn_global_load_lds(
        (const __attribute__((address_space(1))) void*)(uintptr_t)g,
        (__attribute__((address_space(3))) void*)(unsigned)(uintptr_t)l,
        16, 0, 0);
}
#endif

// ---------------------------------------------------------------------------
// Weight transpose+cast: src[K][N] f32 -> dst[N][K] bf16. z = layer*4 + which.
__global__ __launch_bounds__(256) void wtrans(
    const float* __restrict__ Wi, const float* __restrict__ Wo,
    const float* __restrict__ Wx, const float* __restrict__ Wdt,
    u16* __restrict__ WiT, u16* __restrict__ WoT,
    u16* __restrict__ WxT, u16* __restrict__ WdtT)
{
    int l = blockIdx.z >> 2, w = blockIdx.z & 3;
    int K, N; const float* src; u16* dst;
    if (w == 0)      { K = 512;  N = 2048; src = Wi + (size_t)l * 512 * 2048;  dst = WiT + (size_t)l * 2048 * 512; }
    else if (w == 1) { K = 1024; N = 512;  src = Wo + (size_t)l * 1024 * 512;  dst = WoT + (size_t)l * 512 * 1024; }
    else if (w == 2) { K = 1024; N = 64;   src = Wx + (size_t)l * 1024 * 64;   dst = WxT + (size_t)l * 64 * 1024; }
    else             { K = 32;   N = 1024; src = Wdt + (size_t)l * 32 * 1024;  dst = WdtT + (size_t)l * 1024 * 32; }
    int n0 = blockIdx.x * 64, k0 = blockIdx.y * 64;
    if (n0 >= N || k0 >= K) return;
    __shared__ u16 tile[64][65];
    int tn = threadIdx.x & 63, tr = threadIdx.x >> 6;
    for (int r = tr; r < 64; r += 4) {
        int k = k0 + r;
        if (k < K && n0 + tn < N)
            tile[r][tn] = f2bf(src[(size_t)k * N + n0 + tn]);
    }
    __syncthreads();
    for (int r = tr; r < 64; r += 4) {
        int n = n0 + r, k = k0 + tn;
        if (n < N && k < K)
            dst[(size_t)n * K + k] = tile[tn][r];
    }
}

// ---------------------------------------------------------------------------
// cast f32 -> bf16 (x input)
__global__ void cast_bf16(const float4* __restrict__ in, ushort4* __restrict__ out, int n4) {
    int i = blockIdx.x * 256 + threadIdx.x;
    if (i < n4) {
        float4 v = in[i];
        out[i] = make_ushort4(f2bf(v.x), f2bf(v.y), f2bf(v.z), f2bf(v.w));
    }
}

// ---------------------------------------------------------------------------
// m97-style async-staged MFMA bf16 GEMM. A[M][lda] bf16, W[N][ldb] bf16
// (pre-transposed), C typed CT. Tile TM x TN, 4 waves (2x2), BK=32.
// Staging: global_load_lds width=16; XOR k-group swizzle applied on the
// GLOBAL address (LDS dest must be lane-linear) -> LDS image identical to the
// verified register-staged layout; fragment path unchanged (rounds 4-8).
// EP: 0 = LDS-staged wide store; 2 = atomicAdd f32 (split-K accumulate).
// XS: XCD swizzle for in_proj's 16x32 grid (1-D launch).
template <int TM, int TN, int EP, int XS, typename CT>
__global__ __launch_bounds__(256) void gemm_a(
    const u16* __restrict__ A, const u16* __restrict__ W, CT* __restrict__ C,
    int lda, int ldb, int ldc, int kchunk)
{
    constexpr int NI = TM / 32, NJ = TN / 32;
    constexpr int SLOTS = (TM + TN) / 64;
    constexpr int CSTRIDE = TN * (int)sizeof(CT) + 16;
    constexpr int CBYTES = 32 * CSTRIDE;
    constexpr int SBYTES = (TM + TN) * 64;
    constexpr int LBYTES = (EP == 0 && CBYTES > SBYTES) ? CBYTES : SBYTES;
    __shared__ char lds[LBYTES];

    const int tid = threadIdx.x;
    const int lane = tid & 63;
    const int wave = tid >> 6;
    const int wm = wave >> 1, wn = wave & 1;
    const int lm = lane & 15, quad = lane >> 4;

    int bx, by;
    if (XS) {   // 16x32 grid; XCD (bid&7) owns an 8x8 block-tile patch
        int bid = blockIdx.x;
        int xcd = bid & 7, idx = bid >> 3;
        by = (xcd & 3) * 8 + (idx & 7);
        bx = (xcd >> 2) * 8 + (idx >> 3);
    } else { bx = blockIdx.x; by = blockIdx.y; }
    const int row0 = by * TM, col0 = bx * TN;
    const int kstart = blockIdx.z * kchunk;

    const int g = tid & 3;
    const u16* gp[SLOTS];
    char* lb[SLOTS];
#pragma unroll
    for (int s = 0; s < SLOTS; ++s) {
        int r = s * 64 + (tid >> 2);
        int gg = (g ^ (r & 3)) * 8;          // xor'd k-group on the global side
        if (r < TM) gp[s] = A + (size_t)(row0 + r) * lda + kstart + gg;
        else        gp[s] = W + (size_t)(col0 + r - TM) * ldb + kstart + gg;
        lb[s] = (char*)lds + (s * 64 + wave * 16) * 64;   // wave-uniform base
    }

    f32x4 acc[NI][NJ];
#pragma unroll
    for (int i = 0; i < NI; ++i)
#pragma unroll
        for (int j = 0; j < NJ; ++j) acc[i][j] = (f32x4){0.f, 0.f, 0.f, 0.f};

    for (int k0 = 0; k0 < kchunk; k0 += 32) {
#if HAS_ASYNC
#pragma unroll
        for (int s = 0; s < SLOTS; ++s) { gld_lds16(gp[s], lb[s]); gp[s] += 32; }
#else
#pragma unroll
        for (int s = 0; s < SLOTS; ++s) {
            uint4 v = *(const uint4*)gp[s]; gp[s] += 32;
            int r = s * 64 + (tid >> 2);
            *(uint4*)(lds + r * 64 + (g << 4)) = v;   // content pre-xor'd
        }
#endif
        __syncthreads();   // drains vmcnt (async DMA landed) + barrier

        bf16x8 af[NI], bf[NJ];
#pragma unroll
        for (int i = 0; i < NI; ++i) {
            int r = wm * (TM / 2) + i * 16 + lm;
            af[i] = *(const bf16x8*)(lds + r * 64 + ((quad ^ (lm & 3)) << 4));
        }
#pragma unroll
        for (int j = 0; j < NJ; ++j) {
            int r = TM + wn * (TN / 2) + j * 16 + lm;
            bf[j] = *(const bf16x8*)(lds + r * 64 + ((quad ^ (lm & 3)) << 4));
        }
#pragma unroll
        for (int i = 0; i < NI; ++i)
#pragma unroll
            for (int j = 0; j < NJ; ++j)
                acc[i][j] = __builtin_amdgcn_mfma_f32_16x16x32_bf16(
                    af[i], bf[j], acc[i][j], 0, 0, 0);
        __syncthreads();   // frag reads done before next stage overwrites
    }

    if (EP == 2) {   // split-K atomic accumulate (f32 C)
#pragma unroll
        for (int i = 0; i < NI; ++i)
#pragma unroll
            for (int j = 0; j < NJ; ++j)
#pragma unroll
                for (int r = 0; r < 4; ++r) {
                    int row = row0 + wm * (TM / 2) + i * 16 + quad * 4 + r;
                    int col = col0 + wn * (TN / 2) + j * 16 + lm;
                    atomicAdd((float*)C + (size_t)row * ldc + col, acc[i][j][r]);
                }
        return;
    }

    // LDS-staged wide-store epilogue
#pragma unroll
    for (int i = 0; i < NI; ++i) {
        __syncthreads();
#pragma unroll
        for (int j = 0; j < NJ; ++j) {
#pragma unroll
            for (int r = 0; r < 4; ++r) {
                int lr = wm * 16 + quad * 4 + r;
                int lc = wn * (TN / 2) + j * 16 + lm;
                float val = acc[i][j][r];
                if (sizeof(CT) == 2)
                    *(u16*)(lds + lr * CSTRIDE + lc * 2) = f2bf(val);
                else
                    *(float*)(lds + lr * CSTRIDE + lc * 4) = val;
            }
        }
        __syncthreads();
        constexpr int TPR = TN * (int)sizeof(CT) / 16;
        int seg = tid % TPR;
        for (int rr = tid / TPR; rr < 32; rr += 256 / TPR) {
            int gr = row0 + (rr >> 4) * (TM / 2) + i * 16 + (rr & 15);
            *(uint4*)((char*)(C + (size_t)gr * ldc + col0) + seg * 16) =
                *(const uint4*)(lds + rr * CSTRIDE + seg * 16);
        }
    }
}

// ---------------------------------------------------------------------------
// dt_proj: delta = softplus(dbc[:, :32] @ Wdt + bdt). K=32 -> single MFMA
// k-iter. A is f32 (dbc), packed to bf16 during staging. TM=TN=128, u16 out.
__global__ __launch_bounds__(256) void gemm_dt(
    const float* __restrict__ A, const u16* __restrict__ W, u16* __restrict__ C,
    const float* __restrict__ bias)
{
    __shared__ char lds[16384];
    const int tid = threadIdx.x;
    const int lane = tid & 63, wave = tid >> 6;
    const int wm = wave >> 1, wn = wave & 1;
    const int lm = lane & 15, quad = lane >> 4;
    const int row0 = blockIdx.y * 128, col0 = blockIdx.x * 128;
    const int g = tid & 3;

#pragma unroll
    for (int s = 0; s < 4; ++s) {
        int r = s * 64 + (tid >> 2);
        uint4 w;
        if (r < 128) {
            const float* p = A + (size_t)(row0 + r) * NX + g * 8;
            float4 a0 = *(const float4*)p, a1 = *(const float4*)(p + 4);
            w.x = pack_bf16(a0.x, a0.y); w.y = pack_bf16(a0.z, a0.w);
            w.z = pack_bf16(a1.x, a1.y); w.w = pack_bf16(a1.z, a1.w);
        } else {
            w = *(const uint4*)(W + (size_t)(col0 + r - 128) * 32 + g * 8);
        }
        *(uint4*)(lds + r * 64 + (((g ^ (r & 3))) << 4)) = w;
    }
    __syncthreads();

    bf16x8 af[4], bf[4];
#pragma unroll
    for (int i = 0; i < 4; ++i) {
        int r = wm * 64 + i * 16 + lm;
        af[i] = *(const bf16x8*)(lds + r * 64 + ((quad ^ (lm & 3)) << 4));
    }
#pragma unroll
    for (int j = 0; j < 4; ++j) {
        int r = 128 + wn * 64 + j * 16 + lm;
        bf[j] = *(const bf16x8*)(lds + r * 64 + ((quad ^ (lm & 3)) << 4));
    }
    f32x4 acc[4][4];
#pragma unroll
    for (int i = 0; i < 4; ++i)
#pragma unroll
        for (int j = 0; j < 4; ++j)
            acc[i][j] = __builtin_amdgcn_mfma_f32_16x16x32_bf16(
                af[i], bf[j], (f32x4){0.f, 0.f, 0.f, 0.f}, 0, 0, 0);

    constexpr int CSTRIDE = 128 * 2 + 16;
#pragma unroll
    for (int i = 0; i < 4; ++i) {
        __syncthreads();
#pragma unroll
        for (int j = 0; j < 4; ++j) {
#pragma unroll
            for (int r = 0; r < 4; ++r) {
                int lr = wm * 16 + quad * 4 + r;
                int lc = wn * 64 + j * 16 + lm;
                float val = acc[i][j][r] + bias[col0 + lc];
                val = fmaxf(val, 0.f) + log1pf(__expf(-fabsf(val)));
                *(u16*)(lds + lr * CSTRIDE + lc * 2) = f2bf(val);
            }
        }
        __syncthreads();
        int seg = tid & 15;
        for (int rr = tid >> 4; rr < 32; rr += 16) {
            int gr = row0 + (rr >> 4) * 64 + i * 16 + (rr & 15);
            *(uint4*)((char*)(C + (size_t)gr * DI + col0) + seg * 16) =
                *(const uint4*)(lds + rr * CSTRIDE + seg * 16);
        }
    }
}

// ---------------------------------------------------------------------------
// depthwise causal conv (kernel 4) + bias + SiLU; bf16 in (xz), bf16 out (xs)
__global__ void conv_silu_kernel(const u16* __restrict__ xz,
                                 const float* __restrict__ cw, const float* __restrict__ cb,
                                 ushort4* __restrict__ xs)
{
    int i = blockIdx.x * 256 + threadIdx.x;   // 0 .. 1M-1 (d-quads)
    int d = (i & 255) * 4;
    int bt = i >> 8;
    int t = bt & (LL - 1);
    float a0 = cb[d], a1 = cb[d + 1], a2 = cb[d + 2], a3 = cb[d + 3];
    float4 w0 = *(const float4*)(cw + (size_t)d * 4);
    float4 w1 = *(const float4*)(cw + (size_t)(d + 1) * 4);
    float4 w2 = *(const float4*)(cw + (size_t)(d + 2) * 4);
    float4 w3 = *(const float4*)(cw + (size_t)(d + 3) * 4);
    const float* wp0 = (const float*)&w0;
    const float* wp1 = (const float*)&w1;
    const float* wp2 = (const float*)&w2;
    const float* wp3 = (const float*)&w3;
#pragma unroll
    for (int k = 0; k < 4; ++k) {
        int tt = t - 3 + k;
        if (tt >= 0) {
            ushort4 xv = *(const ushort4*)(xz + (size_t)(bt - 3 + k) * 2048 + d);
            a0 = fmaf(bf2f(xv.x), wp0[k], a0);
            a1 = fmaf(bf2f(xv.y), wp1[k], a1);
            a2 = fmaf(bf2f(xv.z), wp2[k], a2);
            a3 = fmaf(bf2f(xv.w), wp3[k], a3);
        }
    }
    xs[i] = make_ushort4(
        f2bf(a0 / (1.f + __expf(-a0))), f2bf(a1 / (1.f + __expf(-a1))),
        f2bf(a2 / (1.f + __expf(-a2))), f2bf(a3 / (1.f + __expf(-a3))));
}

// ---------------------------------------------------------------------------
// Chunk-parallel scan, register-state (one thread = all 16 states of (b,chunk,d))
__global__ __launch_bounds__(256) void scan_pass1(
    const u16* __restrict__ delta, const u16* __restrict__ xs,
    const float* __restrict__ dbc, const float* __restrict__ A_log,
    float* __restrict__ P, float* __restrict__ Q)
{
    const int dgrp = blockIdx.x & 3;
    const int chunk = (blockIdx.x >> 2) & (NCH - 1);
    const int b = blockIdx.x >> 7;
    const int d = dgrp * 256 + threadIdx.x;
    const int t0 = b * LL + chunk * CH;

    __shared__ float sB[CH][DS];
    {
        int i = threadIdx.x;
        int row = i >> 3, col = (i & 7) * 2;
        float2 v = *(const float2*)(dbc + (size_t)(t0 + row) * NX + DTR + col);
        sB[row][col] = v.x; sB[row][col + 1] = v.y;
    }
    float An[DS];
#pragma unroll
    for (int n = 0; n < DS; ++n) An[n] = -__expf(A_log[d * DS + n]);
    __syncthreads();

    float Pv[DS], h[DS];
#pragma unroll
    for (int n = 0; n < DS; ++n) { Pv[n] = 1.f; h[n] = 0.f; }

    const u16* dp = delta + (size_t)t0 * DI + d;
    const u16* xp = xs + (size_t)t0 * DI + d;
#pragma unroll 4
    for (int t = 0; t < CH; ++t) {
        float dlt = bf2f(dp[t * DI]);
        float du = dlt * bf2f(xp[t * DI]);
#pragma unroll
        for (int n = 0; n < DS; ++n) {
            float dA = __expf(dlt * An[n]);
            Pv[n] *= dA;
            h[n] = fmaf(dA, h[n], du * sB[t][n]);
        }
    }
    size_t base = ((size_t)(b * NCH + chunk) * DI + d) * DS;
    float4* Pp = (float4*)(P + base);
    float4* Qp = (float4*)(Q + base);
#pragma unroll
    for (int g = 0; g < 4; ++g) {
        Pp[g] = make_float4(Pv[g * 4], Pv[g * 4 + 1], Pv[g * 4 + 2], Pv[g * 4 + 3]);
        Qp[g] = make_float4(h[g * 4], h[g * 4 + 1], h[g * 4 + 2], h[g * 4 + 3]);
    }
}

__global__ __launch_bounds__(256) void scan_pass2(float* __restrict__ P,
                                                  const float* __restrict__ Q)
{
    int tid = blockIdx.x * 256 + threadIdx.x;
    int n = tid & 15;
    int d = (tid >> 4) & (DI - 1);
    int b = tid >> 14;
    float carry = 0.f;
    for (int c = 0; c < NCH; ++c) {
        size_t i = ((size_t)(b * NCH + c) * DI + d) * DS + n;
        float Pv = P[i], Qv = Q[i];
        P[i] = carry;
        carry = fmaf(Pv, carry, Qv);
    }
}

// pass3: re-run from H_in; y = sum_n h_n C_n + D-skip, silu(z) gate -> y bf16
__global__ __launch_bounds__(256) void scan_pass3(
    const u16* __restrict__ delta, const u16* __restrict__ xs,
    const float* __restrict__ dbc, const u16* __restrict__ xz,
    const float* __restrict__ A_log, const float* __restrict__ Dsk,
    const float* __restrict__ Hin, u16* __restrict__ yb)
{
    const int dgrp = blockIdx.x & 3;
    const int chunk = (blockIdx.x >> 2) & (NCH - 1);
    const int b = blockIdx.x >> 7;
    const int d = dgrp * 256 + threadIdx.x;
    const int t0 = b * LL + chunk * CH;

    __shared__ float sBC[CH][32];   // cols 0..15 = B, 16..31 = C
    {
        int i = threadIdx.x;
        int row = i >> 3, col = (i & 7) * 4;
        float4 v = *(const float4*)(dbc + (size_t)(t0 + row) * NX + DTR + col);
        *(float4*)&sBC[row][col] = v;
    }
    float An[DS];
#pragma unroll
    for (int n = 0; n < DS; ++n) An[n] = -__expf(A_log[d * DS + n]);
    const float Dd = Dsk[d];

    float h[DS];
    {
        size_t base = ((size_t)(b * NCH + chunk) * DI + d) * DS;
        const float4* Hp = (const float4*)(Hin + base);
#pragma unroll
        for (int g = 0; g < 4; ++g) {
            float4 v = Hp[g];
            h[g * 4] = v.x; h[g * 4 + 1] = v.y; h[g * 4 + 2] = v.z; h[g * 4 + 3] = v.w;
        }
    }
    __syncthreads();

    const u16* dp = delta + (size_t)t0 * DI + d;
    const u16* xp = xs + (size_t)t0 * DI + d;
    const u16* zp = xz + (size_t)t0 * 2048 + DI + d;
    u16* yp = yb + (size_t)t0 * DI + d;

#pragma unroll 4
    for (int t = 0; t < CH; ++t) {
        float dlt = bf2f(dp[t * DI]);
        float xv  = bf2f(xp[t * DI]);
        float zv  = bf2f(zp[t * 2048]);
        float du = dlt * xv;
        float y = 0.f;
#pragma unroll
        for (int n = 0; n < DS; ++n) {
            float dA = __expf(dlt * An[n]);
            h[n] = fmaf(dA, h[n], du * sBC[t][n]);
            y = fmaf(h[n], sBC[t][DS + n], y);
        }
        y += xv * Dd;
        float sz = zv / (1.f + __expf(-zv));
        yp[t * DI] = f2bf(y * sz);
    }
}

// ---------------------------------------------------------------------------
// residual add + LayerNorm; writes f32 hout; optionally bf16 copy (next GEMM A)
__global__ __launch_bounds__(512) void ln_kernel(
    const float* __restrict__ o, const float* __restrict__ hprev,
    const float* __restrict__ g, const float* __restrict__ bta,
    float* __restrict__ hout, u16* __restrict__ hbf, int wb)
{
    int row = blockIdx.x, c = threadIdx.x;
    size_t off = (size_t)row * DM + c;
    float v = o[off] + hprev[off];
    float s1 = v, s2 = v * v;
#pragma unroll
    for (int m = 32; m >= 1; m >>= 1) {
        s1 += __shfl_xor(s1, m);
        s2 += __shfl_xor(s2, m);
    }
    __shared__ float r1[8], r2[8];
    __shared__ float stats[2];
    int w = c >> 6;
    if ((c & 63) == 0) { r1[w] = s1; r2[w] = s2; }
    __syncthreads();
    if (c == 0) {
        float a = 0.f, q = 0.f;
        for (int i = 0; i < 8; ++i) { a += r1[i]; q += r2[i]; }
        float mean = a / (float)DM;
        float var = q / (float)DM - mean * mean;
        stats[0] = mean;
        stats[1] = rsqrtf(var + 1e-5f);
    }
    __syncthreads();
    float res = (v - stats[0]) * stats[1] * g[c] + bta[c];
    hout[off] = res;
    if (wb) hbf[off] = f2bf(res);
}

// ---------------------------------------------------------------------------
extern "C" void kernel_launch(void* const* d_in, const int* in_sizes, int n_in,
                              void* d_out, int out_size, void* d_ws, size_t ws_size,
                              hipStream_t stream)
{
    const float* x    = (const float*)d_in[0];
    const float* Wi   = (const float*)d_in[1];
    const float* cw   = (const float*)d_in[2];
    const float* cb   = (const float*)d_in[3];
    const float* Wx   = (const float*)d_in[4];
    const float* Wdt  = (const float*)d_in[5];
    const float* bdt  = (const float*)d_in[6];
    const float* Alog = (const float*)d_in[7];
    const float* Dsk  = (const float*)d_in[8];
    const float* Wo   = (const float*)d_in[9];
    const float* lng  = (const float*)d_in[10];
    const float* lnb  = (const float*)d_in[11];

    float* fw   = (float*)d_ws;
    float* h    = fw;                      // 2M f32
    float* ob   = h + 2097152;             // 2M f32
    float* dbc  = ob + 2097152;            // 256K f32 (atomic split-K target)
    float* Pb   = dbc + 262144;            // 2M f32
    float* Qb   = Pb + 2097152;            // 2M f32
    u16* xzb    = (u16*)(Qb + 2097152);    // 8M u16 (4096 x 2048)
    u16* xsbf   = xzb + 8388608;           // 4M u16
    u16* abf    = xsbf + 4194304;          // 4M u16 (x/h bf16, then y bf16)
    u16* dltb   = abf + 4194304;           // 4M u16
    u16* WiT    = dltb + 4194304;          // 2 x 1M u16
    u16* WoT    = WiT + 2097152;           // 2 x 512K u16
    u16* WxT    = WoT + 1048576;           // 2 x 64K u16
    u16* WdtT   = WxT + 131072;            // 2 x 32K u16

    // one-time per call: x -> bf16, all weights -> [N][K] bf16
    cast_bf16<<<2048, 256, 0, stream>>>((const float4*)x, (ushort4*)abf, 524288);
    wtrans<<<dim3(32, 16, 8), 256, 0, stream>>>(Wi, Wo, Wx, Wdt, WiT, WoT, WxT, WdtT);

    for (int l = 0; l < 2; ++l) {
        const float* hin = (l == 0) ? x : h;
        const u16* WiTl  = WiT  + (size_t)l * 2048 * 512;
        const u16* WoTl  = WoT  + (size_t)l * 512 * 1024;
        const u16* WxTl  = WxT  + (size_t)l * 64 * 1024;
        const u16* WdtTl = WdtT + (size_t)l * 1024 * 32;

        // xz = h @ Wi  (4096 x 2048, K=512) -> bf16; async staging, XCD swizzle
        gemm_a<128, 128, 0, 1, u16><<<512, 256, 0, stream>>>(
            abf, WiTl, xzb, 512, 512, 2048, 512);

        // xs = silu(conv(xin) + cb) -> bf16
        conv_silu_kernel<<<4096, 256, 0, stream>>>(
            xzb, cw + (size_t)l * DI * 4, cb + (size_t)l * DI, (ushort4*)xsbf);

        // dbc = xs @ Wx  (4096 x 64, K=1024): split-K=8, atomic accumulate
        hipMemsetAsync(dbc, 0, (size_t)MROWS * NX * sizeof(float), stream);
        gemm_a<128, 64, 2, 0, float><<<dim3(1, 32, 8), 256, 0, stream>>>(
            xsbf, WxTl, dbc, 1024, 1024, 64, 128);

        // delta = softplus(dbc[:, :32] @ Wdt + bdt) -> bf16 (single k-iter)
        gemm_dt<<<dim3(8, 32), 256, 0, stream>>>(
            dbc, WdtTl, dltb, bdt + (size_t)l * DI);

        // chunk-parallel selective scan -> y bf16 (into abf)
        scan_pass1<<<BB * NCH * 4, 256, 0, stream>>>(
            dltb, xsbf, dbc, Alog + (size_t)l * DI * DS, Pb, Qb);
        scan_pass2<<<256, 256, 0, stream>>>(Pb, Qb);
        scan_pass3<<<BB * NCH * 4, 256, 0, stream>>>(
            dltb, xsbf, dbc, xzb, Alog + (size_t)l * DI * DS, Dsk + (size_t)l * DI,
            Pb, abf);

        // o = y @ Wo  (4096 x 512, K=1024) -> f32; async staging
        gemm_a<64, 128, 0, 0, float><<<dim3(4, 64), 256, 0, stream>>>(
            abf, WoTl, ob, 1024, 1024, 512, 1024);

        // h = LN(o + hin); l=0 also writes bf16 h into abf; l=1 -> d_out
        ln_kernel<<<MROWS, 512, 0, stream>>>(
            ob, hin, lng + (size_t)l * DM, lnb + (size_t)l * DM,
            (l == 1) ? (float*)d_out : h, abf, l == 0);
    }
}

// Round 10
// 393.646 us; speedup vs baseline: 1.3409x; 1.0521x over previous
//
#include <hip/hip_runtime.h>
#include <cstdint>

// Problem constants
#define BB 4
#define LL 1024
#define DM 512
#define DI 1024
#define DS 16
#define DTR 32
#define NX 64          // DTR + 2*DS
#define MROWS 4096     // B*L
#define CH 32          // scan chunk length
#define NCH 32         // LL / CH

typedef unsigned short u16;
typedef __attribute__((ext_vector_type(8))) short bf16x8;
typedef __attribute__((ext_vector_type(4))) float f32x4;

#if defined(__has_builtin)
#if __has_builtin(__builtin_amdgcn_global_load_lds)
#define HAS_ASYNC 1
#endif
#endif
#ifndef HAS_ASYNC
#define HAS_ASYNC 0
#endif

__device__ __forceinline__ float bf2f(u16 u) {
    union { unsigned int i; float f; } v;
    v.i = ((unsigned int)u) << 16;
    return v.f;
}
__device__ __forceinline__ u16 f2bf(float f) {
    union { float f; unsigned u; } v;
    v.f = f;
    return (u16)((v.u + 0x7fffu + ((v.u >> 16) & 1u)) >> 16);
}
__device__ __forceinline__ unsigned pack_bf16(float a, float b) {
    union { float f; unsigned u; } ua, ub;
    ua.f = a; ub.f = b;
    unsigned ra = (ua.u + 0x7fffu + ((ua.u >> 16) & 1u)) >> 16;
    unsigned rb = (ub.u + 0x7fffu + ((ub.u >> 16) & 1u)) & 0xffff0000u;
    return ra | rb;
}

#if HAS_ASYNC
// async global -> LDS, 16 B per lane. LDS dest = wave-uniform base + lane*16.
__device__ __forceinline__ void gld_lds16(const void* g, void* l) {
    __builtin_amdgcn_global_load_lds(
        (const __attribute__((address_space(1))) void*)(uintptr_t)g,
        (__attribute__((address_space(3))) void*)(unsigned)(uintptr_t)l,
        16, 0, 0);
}
#endif

// ---------------------------------------------------------------------------
// Weight transpose+cast: src[K][N] f32 -> dst[N][K] bf16. z = layer*4 + which.
__global__ __launch_bounds__(256) void wtrans(
    const float* __restrict__ Wi, const float* __restrict__ Wo,
    const float* __restrict__ Wx, const float* __restrict__ Wdt,
    u16* __restrict__ WiT, u16* __restrict__ WoT,
    u16* __restrict__ WxT, u16* __restrict__ WdtT)
{
    int l = blockIdx.z >> 2, w = blockIdx.z & 3;
    int K, N; const float* src; u16* dst;
    if (w == 0)      { K = 512;  N = 2048; src = Wi + (size_t)l * 512 * 2048;  dst = WiT + (size_t)l * 2048 * 512; }
    else if (w == 1) { K = 1024; N = 512;  src = Wo + (size_t)l * 1024 * 512;  dst = WoT + (size_t)l * 512 * 1024; }
    else if (w == 2) { K = 1024; N = 64;   src = Wx + (size_t)l * 1024 * 64;   dst = WxT + (size_t)l * 64 * 1024; }
    else             { K = 32;   N = 1024; src = Wdt + (size_t)l * 32 * 1024;  dst = WdtT + (size_t)l * 1024 * 32; }
    int n0 = blockIdx.x * 64, k0 = blockIdx.y * 64;
    if (n0 >= N || k0 >= K) return;
    __shared__ u16 tile[64][65];
    int tn = threadIdx.x & 63, tr = threadIdx.x >> 6;
    for (int r = tr; r < 64; r += 4) {
        int k = k0 + r;
        if (k < K && n0 + tn < N)
            tile[r][tn] = f2bf(src[(size_t)k * N + n0 + tn]);
    }
    __syncthreads();
    for (int r = tr; r < 64; r += 4) {
        int n = n0 + r, k = k0 + tn;
        if (n < N && k < K)
            dst[(size_t)n * K + k] = tile[tn][r];
    }
}

// ---------------------------------------------------------------------------
// cast f32 -> bf16 (x input)
__global__ void cast_bf16(const float4* __restrict__ in, ushort4* __restrict__ out, int n4) {
    int i = blockIdx.x * 256 + threadIdx.x;
    if (i < n4) {
        float4 v = in[i];
        out[i] = make_ushort4(f2bf(v.x), f2bf(v.y), f2bf(v.z), f2bf(v.w));
    }
}

// ---------------------------------------------------------------------------
// m97-style async-staged MFMA bf16 GEMM. A[M][lda] bf16, W[N][ldb] bf16
// (pre-transposed), C typed CT. Tile TM x TN, 4 waves (2x2), BK=32.
// Staging: global_load_lds width=16; XOR k-group swizzle applied on the
// GLOBAL address (LDS dest lane-linear); fragment path verified rounds 4-9.
// Epilogue: LDS-staged wide stores. Split-K via blockIdx.z writes partials to
// distinct C slices (deterministic -- no atomics).
// XS: XCD swizzle for in_proj's 16x32 grid (1-D launch).
template <int TM, int TN, int XS, typename CT>
__global__ __launch_bounds__(256) void gemm_a(
    const u16* __restrict__ A, const u16* __restrict__ W, CT* __restrict__ C,
    int lda, int ldb, int ldc, int kchunk)
{
    constexpr int NI = TM / 32, NJ = TN / 32;
    constexpr int SLOTS = (TM + TN) / 64;
    constexpr int CSTRIDE = TN * (int)sizeof(CT) + 16;
    constexpr int CBYTES = 32 * CSTRIDE;
    constexpr int SBYTES = (TM + TN) * 64;
    constexpr int LBYTES = (CBYTES > SBYTES) ? CBYTES : SBYTES;
    __shared__ char lds[LBYTES];

    const int tid = threadIdx.x;
    const int lane = tid & 63;
    const int wave = tid >> 6;
    const int wm = wave >> 1, wn = wave & 1;
    const int lm = lane & 15, quad = lane >> 4;

    int bx, by;
    if (XS) {   // 16x32 grid; XCD (bid&7) owns an 8x8 block-tile patch
        int bid = blockIdx.x;
        int xcd = bid & 7, idx = bid >> 3;
        by = (xcd & 3) * 8 + (idx & 7);
        bx = (xcd >> 2) * 8 + (idx >> 3);
    } else { bx = blockIdx.x; by = blockIdx.y; }
    const int row0 = by * TM, col0 = bx * TN;
    const int kstart = blockIdx.z * kchunk;
    CT* Cz = C + (size_t)blockIdx.z * (size_t)(gridDim.y * TM) * ldc;

    const int g = tid & 3;
    const u16* gp[SLOTS];
    char* lb[SLOTS];
#pragma unroll
    for (int s = 0; s < SLOTS; ++s) {
        int r = s * 64 + (tid >> 2);
        int gg = (g ^ (r & 3)) * 8;          // xor'd k-group on the global side
        if (r < TM) gp[s] = A + (size_t)(row0 + r) * lda + kstart + gg;
        else        gp[s] = W + (size_t)(col0 + r - TM) * ldb + kstart + gg;
        lb[s] = (char*)lds + (s * 64 + wave * 16) * 64;   // wave-uniform base
    }

    f32x4 acc[NI][NJ];
#pragma unroll
    for (int i = 0; i < NI; ++i)
#pragma unroll
        for (int j = 0; j < NJ; ++j) acc[i][j] = (f32x4){0.f, 0.f, 0.f, 0.f};

    for (int k0 = 0; k0 < kchunk; k0 += 32) {
#if HAS_ASYNC
#pragma unroll
        for (int s = 0; s < SLOTS; ++s) { gld_lds16(gp[s], lb[s]); gp[s] += 32; }
#else
#pragma unroll
        for (int s = 0; s < SLOTS; ++s) {
            uint4 v = *(const uint4*)gp[s]; gp[s] += 32;
            int r = s * 64 + (tid >> 2);
            *(uint4*)(lds + r * 64 + (g << 4)) = v;   // content pre-xor'd
        }
#endif
        __syncthreads();   // drains vmcnt (async DMA landed) + barrier

        bf16x8 af[NI], bf[NJ];
#pragma unroll
        for (int i = 0; i < NI; ++i) {
            int r = wm * (TM / 2) + i * 16 + lm;
            af[i] = *(const bf16x8*)(lds + r * 64 + ((quad ^ (lm & 3)) << 4));
        }
#pragma unroll
        for (int j = 0; j < NJ; ++j) {
            int r = TM + wn * (TN / 2) + j * 16 + lm;
            bf[j] = *(const bf16x8*)(lds + r * 64 + ((quad ^ (lm & 3)) << 4));
        }
#pragma unroll
        for (int i = 0; i < NI; ++i)
#pragma unroll
            for (int j = 0; j < NJ; ++j)
                acc[i][j] = __builtin_amdgcn_mfma_f32_16x16x32_bf16(
                    af[i], bf[j], acc[i][j], 0, 0, 0);
        __syncthreads();   // frag reads done before next stage overwrites
    }

    // LDS-staged wide-store epilogue
#pragma unroll
    for (int i = 0; i < NI; ++i) {
        __syncthreads();
#pragma unroll
        for (int j = 0; j < NJ; ++j) {
#pragma unroll
            for (int r = 0; r < 4; ++r) {
                int lr = wm * 16 + quad * 4 + r;
                int lc = wn * (TN / 2) + j * 16 + lm;
                float val = acc[i][j][r];
                if (sizeof(CT) == 2)
                    *(u16*)(lds + lr * CSTRIDE + lc * 2) = f2bf(val);
                else
                    *(float*)(lds + lr * CSTRIDE + lc * 4) = val;
            }
        }
        __syncthreads();
        constexpr int TPR = TN * (int)sizeof(CT) / 16;
        int seg = tid % TPR;
        for (int rr = tid / TPR; rr < 32; rr += 256 / TPR) {
            int gr = row0 + (rr >> 4) * (TM / 2) + i * 16 + (rr & 15);
            *(uint4*)((char*)(Cz + (size_t)gr * ldc + col0) + seg * 16) =
                *(const uint4*)(lds + rr * CSTRIDE + seg * 16);
        }
    }
}

// ---------------------------------------------------------------------------
// reduce x_proj split-K partials: dbc = sum_z pxp[z]  (f32)
__global__ __launch_bounds__(256) void reduce_dbc(
    const float4* __restrict__ px, float4* __restrict__ dbc)
{
    int i = blockIdx.x * 256 + threadIdx.x;   // 65536 float4s
    float4 s = px[i];
#pragma unroll
    for (int z = 1; z < 8; ++z) {
        float4 v = px[(size_t)z * 65536 + i];
        s.x += v.x; s.y += v.y; s.z += v.z; s.w += v.w;
    }
    dbc[i] = s;
}

// ---------------------------------------------------------------------------
// dt_proj: delta = softplus(dbc[:, :32] @ Wdt + bdt). K=32 -> single MFMA
// k-iter. A is f32 (dbc), packed to bf16 during staging. TM=TN=128, u16 out.
__global__ __launch_bounds__(256) void gemm_dt(
    const float* __restrict__ A, const u16* __restrict__ W, u16* __restrict__ C,
    const float* __restrict__ bias)
{
    __shared__ char lds[16384];
    const int tid = threadIdx.x;
    const int lane = tid & 63, wave = tid >> 6;
    const int wm = wave >> 1, wn = wave & 1;
    const int lm = lane & 15, quad = lane >> 4;
    const int row0 = blockIdx.y * 128, col0 = blockIdx.x * 128;
    const int g = tid & 3;

#pragma unroll
    for (int s = 0; s < 4; ++s) {
        int r = s * 64 + (tid >> 2);
        uint4 w;
        if (r < 128) {
            const float* p = A + (size_t)(row0 + r) * NX + g * 8;
            float4 a0 = *(const float4*)p, a1 = *(const float4*)(p + 4);
            w.x = pack_bf16(a0.x, a0.y); w.y = pack_bf16(a0.z, a0.w);
            w.z = pack_bf16(a1.x, a1.y); w.w = pack_bf16(a1.z, a1.w);
        } else {
            w = *(const uint4*)(W + (size_t)(col0 + r - 128) * 32 + g * 8);
        }
        *(uint4*)(lds + r * 64 + (((g ^ (r & 3))) << 4)) = w;
    }
    __syncthreads();

    bf16x8 af[4], bf[4];
#pragma unroll
    for (int i = 0; i < 4; ++i) {
        int r = wm * 64 + i * 16 + lm;
        af[i] = *(const bf16x8*)(lds + r * 64 + ((quad ^ (lm & 3)) << 4));
    }
#pragma unroll
    for (int j = 0; j < 4; ++j) {
        int r = 128 + wn * 64 + j * 16 + lm;
        bf[j] = *(const bf16x8*)(lds + r * 64 + ((quad ^ (lm & 3)) << 4));
    }
    f32x4 acc[4][4];
#pragma unroll
    for (int i = 0; i < 4; ++i)
#pragma unroll
        for (int j = 0; j < 4; ++j)
            acc[i][j] = __builtin_amdgcn_mfma_f32_16x16x32_bf16(
                af[i], bf[j], (f32x4){0.f, 0.f, 0.f, 0.f}, 0, 0, 0);

    constexpr int CSTRIDE = 128 * 2 + 16;
#pragma unroll
    for (int i = 0; i < 4; ++i) {
        __syncthreads();
#pragma unroll
        for (int j = 0; j < 4; ++j) {
#pragma unroll
            for (int r = 0; r < 4; ++r) {
                int lr = wm * 16 + quad * 4 + r;
                int lc = wn * 64 + j * 16 + lm;
                float val = acc[i][j][r] + bias[col0 + lc];
                val = fmaxf(val, 0.f) + log1pf(__expf(-fabsf(val)));
                *(u16*)(lds + lr * CSTRIDE + lc * 2) = f2bf(val);
            }
        }
        __syncthreads();
        int seg = tid & 15;
        for (int rr = tid >> 4; rr < 32; rr += 16) {
            int gr = row0 + (rr >> 4) * 64 + i * 16 + (rr & 15);
            *(uint4*)((char*)(C + (size_t)gr * DI + col0) + seg * 16) =
                *(const uint4*)(lds + rr * CSTRIDE + seg * 16);
        }
    }
}

// ---------------------------------------------------------------------------
// depthwise causal conv (kernel 4) + bias + SiLU; bf16 in (xz), bf16 out (xs)
__global__ void conv_silu_kernel(const u16* __restrict__ xz,
                                 const float* __restrict__ cw, const float* __restrict__ cb,
                                 ushort4* __restrict__ xs)
{
    int i = blockIdx.x * 256 + threadIdx.x;   // 0 .. 1M-1 (d-quads)
    int d = (i & 255) * 4;
    int bt = i >> 8;
    int t = bt & (LL - 1);
    float a0 = cb[d], a1 = cb[d + 1], a2 = cb[d + 2], a3 = cb[d + 3];
    float4 w0 = *(const float4*)(cw + (size_t)d * 4);
    float4 w1 = *(const float4*)(cw + (size_t)(d + 1) * 4);
    float4 w2 = *(const float4*)(cw + (size_t)(d + 2) * 4);
    float4 w3 = *(const float4*)(cw + (size_t)(d + 3) * 4);
    const float* wp0 = (const float*)&w0;
    const float* wp1 = (const float*)&w1;
    const float* wp2 = (const float*)&w2;
    const float* wp3 = (const float*)&w3;
#pragma unroll
    for (int k = 0; k < 4; ++k) {
        int tt = t - 3 + k;
        if (tt >= 0) {
            ushort4 xv = *(const ushort4*)(xz + (size_t)(bt - 3 + k) * 2048 + d);
            a0 = fmaf(bf2f(xv.x), wp0[k], a0);
            a1 = fmaf(bf2f(xv.y), wp1[k], a1);
            a2 = fmaf(bf2f(xv.z), wp2[k], a2);
            a3 = fmaf(bf2f(xv.w), wp3[k], a3);
        }
    }
    xs[i] = make_ushort4(
        f2bf(a0 / (1.f + __expf(-a0))), f2bf(a1 / (1.f + __expf(-a1))),
        f2bf(a2 / (1.f + __expf(-a2))), f2bf(a3 / (1.f + __expf(-a3))));
}

// ---------------------------------------------------------------------------
// Chunk-parallel scan, register-state (one thread = all 16 states of (b,chunk,d))
__global__ __launch_bounds__(256) void scan_pass1(
    const u16* __restrict__ delta, const u16* __restrict__ xs,
    const float* __restrict__ dbc, const float* __restrict__ A_log,
    float* __restrict__ P, float* __restrict__ Q)
{
    const int dgrp = blockIdx.x & 3;
    const int chunk = (blockIdx.x >> 2) & (NCH - 1);
    const int b = blockIdx.x >> 7;
    const int d = dgrp * 256 + threadIdx.x;
    const int t0 = b * LL + chunk * CH;

    __shared__ float sB[CH][DS];
    {
        int i = threadIdx.x;
        int row = i >> 3, col = (i & 7) * 2;
        float2 v = *(const float2*)(dbc + (size_t)(t0 + row) * NX + DTR + col);
        sB[row][col] = v.x; sB[row][col + 1] = v.y;
    }
    float An[DS];
#pragma unroll
    for (int n = 0; n < DS; ++n) An[n] = -__expf(A_log[d * DS + n]);
    __syncthreads();

    float Pv[DS], h[DS];
#pragma unroll
    for (int n = 0; n < DS; ++n) { Pv[n] = 1.f; h[n] = 0.f; }

    const u16* dp = delta + (size_t)t0 * DI + d;
    const u16* xp = xs + (size_t)t0 * DI + d;
#pragma unroll 4
    for (int t = 0; t < CH; ++t) {
        float dlt = bf2f(dp[t * DI]);
        float du = dlt * bf2f(xp[t * DI]);
#pragma unroll
        for (int n = 0; n < DS; ++n) {
            float dA = __expf(dlt * An[n]);
            Pv[n] *= dA;
            h[n] = fmaf(dA, h[n], du * sB[t][n]);
        }
    }
    size_t base = ((size_t)(b * NCH + chunk) * DI + d) * DS;
    float4* Pp = (float4*)(P + base);
    float4* Qp = (float4*)(Q + base);
#pragma unroll
    for (int g = 0; g < 4; ++g) {
        Pp[g] = make_float4(Pv[g * 4], Pv[g * 4 + 1], Pv[g * 4 + 2], Pv[g * 4 + 3]);
        Qp[g] = make_float4(h[g * 4], h[g * 4 + 1], h[g * 4 + 2], h[g * 4 + 3]);
    }
}

__global__ __launch_bounds__(256) void scan_pass2(float* __restrict__ P,
                                                  const float* __restrict__ Q)
{
    int tid = blockIdx.x * 256 + threadIdx.x;
    int n = tid & 15;
    int d = (tid >> 4) & (DI - 1);
    int b = tid >> 14;
    float carry = 0.f;
    for (int c = 0; c < NCH; ++c) {
        size_t i = ((size_t)(b * NCH + c) * DI + d) * DS + n;
        float Pv = P[i], Qv = Q[i];
        P[i] = carry;
        carry = fmaf(Pv, carry, Qv);
    }
}

// pass3: re-run from H_in; y = sum_n h_n C_n + D-skip, silu(z) gate -> y bf16
__global__ __launch_bounds__(256) void scan_pass3(
    const u16* __restrict__ delta, const u16* __restrict__ xs,
    const float* __restrict__ dbc, const u16* __restrict__ xz,
    const float* __restrict__ A_log, const float* __restrict__ Dsk,
    const float* __restrict__ Hin, u16* __restrict__ yb)
{
    const int dgrp = blockIdx.x & 3;
    const int chunk = (blockIdx.x >> 2) & (NCH - 1);
    const int b = blockIdx.x >> 7;
    const int d = dgrp * 256 + threadIdx.x;
    const int t0 = b * LL + chunk * CH;

    __shared__ float sBC[CH][32];   // cols 0..15 = B, 16..31 = C
    {
        int i = threadIdx.x;
        int row = i >> 3, col = (i & 7) * 4;
        float4 v = *(const float4*)(dbc + (size_t)(t0 + row) * NX + DTR + col);
        *(float4*)&sBC[row][col] = v;
    }
    float An[DS];
#pragma unroll
    for (int n = 0; n < DS; ++n) An[n] = -__expf(A_log[d * DS + n]);
    const float Dd = Dsk[d];

    float h[DS];
    {
        size_t base = ((size_t)(b * NCH + chunk) * DI + d) * DS;
        const float4* Hp = (const float4*)(Hin + base);
#pragma unroll
        for (int g = 0; g < 4; ++g) {
            float4 v = Hp[g];
            h[g * 4] = v.x; h[g * 4 + 1] = v.y; h[g * 4 + 2] = v.z; h[g * 4 + 3] = v.w;
        }
    }
    __syncthreads();

    const u16* dp = delta + (size_t)t0 * DI + d;
    const u16* xp = xs + (size_t)t0 * DI + d;
    const u16* zp = xz + (size_t)t0 * 2048 + DI + d;
    u16* yp = yb + (size_t)t0 * DI + d;

#pragma unroll 4
    for (int t = 0; t < CH; ++t) {
        float dlt = bf2f(dp[t * DI]);
        float xv  = bf2f(xp[t * DI]);
        float zv  = bf2f(zp[t * 2048]);
        float du = dlt * xv;
        float y = 0.f;
#pragma unroll
        for (int n = 0; n < DS; ++n) {
            float dA = __expf(dlt * An[n]);
            h[n] = fmaf(dA, h[n], du * sBC[t][n]);
            y = fmaf(h[n], sBC[t][DS + n], y);
        }
        y += xv * Dd;
        float sz = zv / (1.f + __expf(-zv));
        yp[t * DI] = f2bf(y * sz);
    }
}

// ---------------------------------------------------------------------------
// residual add + LayerNorm; sums two out_proj split-K partials.
// writes f32 hout; optionally bf16 copy (next GEMM A)
__global__ __launch_bounds__(512) void ln_kernel(
    const float* __restrict__ o0, const float* __restrict__ o1,
    const float* __restrict__ hprev,
    const float* __restrict__ g, const float* __restrict__ bta,
    float* __restrict__ hout, u16* __restrict__ hbf, int wb)
{
    int row = blockIdx.x, c = threadIdx.x;
    size_t off = (size_t)row * DM + c;
    float v = o0[off] + o1[off] + hprev[off];
    float s1 = v, s2 = v * v;
#pragma unroll
    for (int m = 32; m >= 1; m >>= 1) {
        s1 += __shfl_xor(s1, m);
        s2 += __shfl_xor(s2, m);
    }
    __shared__ float r1[8], r2[8];
    __shared__ float stats[2];
    int w = c >> 6;
    if ((c & 63) == 0) { r1[w] = s1; r2[w] = s2; }
    __syncthreads();
    if (c == 0) {
        float a = 0.f, q = 0.f;
        for (int i = 0; i < 8; ++i) { a += r1[i]; q += r2[i]; }
        float mean = a / (float)DM;
        float var = q / (float)DM - mean * mean;
        stats[0] = mean;
        stats[1] = rsqrtf(var + 1e-5f);
    }
    __syncthreads();
    float res = (v - stats[0]) * stats[1] * g[c] + bta[c];
    hout[off] = res;
    if (wb) hbf[off] = f2bf(res);
}

// ---------------------------------------------------------------------------
extern "C" void kernel_launch(void* const* d_in, const int* in_sizes, int n_in,
                              void* d_out, int out_size, void* d_ws, size_t ws_size,
                              hipStream_t stream)
{
    const float* x    = (const float*)d_in[0];
    const float* Wi   = (const float*)d_in[1];
    const float* cw   = (const float*)d_in[2];
    const float* cb   = (const float*)d_in[3];
    const float* Wx   = (const float*)d_in[4];
    const float* Wdt  = (const float*)d_in[5];
    const float* bdt  = (const float*)d_in[6];
    const float* Alog = (const float*)d_in[7];
    const float* Dsk  = (const float*)d_in[8];
    const float* Wo   = (const float*)d_in[9];
    const float* lng  = (const float*)d_in[10];
    const float* lnb  = (const float*)d_in[11];

    float* fw   = (float*)d_ws;
    float* h    = fw;                      // 2M f32
    float* ob   = h + 2097152;             // 2 x 2M f32 (out_proj split-K partials)
    float* dbc  = ob + 4194304;            // 256K f32
    float* pxp  = dbc + 262144;            // 2M f32 (8 x 4096 x 64 partials)
    float* Pb   = pxp + 2097152;           // 2M f32
    float* Qb   = Pb + 2097152;            // 2M f32
    u16* xzb    = (u16*)(Qb + 2097152);    // 8M u16 (4096 x 2048)
    u16* xsbf   = xzb + 8388608;           // 4M u16
    u16* abf    = xsbf + 4194304;          // 4M u16 (x/h bf16, then y bf16)
    u16* dltb   = abf + 4194304;           // 4M u16
    u16* WiT    = dltb + 4194304;          // 2 x 1M u16
    u16* WoT    = WiT + 2097152;           // 2 x 512K u16
    u16* WxT    = WoT + 1048576;           // 2 x 64K u16
    u16* WdtT   = WxT + 131072;            // 2 x 32K u16

    // one-time per call: x -> bf16, all weights -> [N][K] bf16
    cast_bf16<<<2048, 256, 0, stream>>>((const float4*)x, (ushort4*)abf, 524288);
    wtrans<<<dim3(32, 16, 8), 256, 0, stream>>>(Wi, Wo, Wx, Wdt, WiT, WoT, WxT, WdtT);

    for (int l = 0; l < 2; ++l) {
        const float* hin = (l == 0) ? x : h;
        const u16* WiTl  = WiT  + (size_t)l * 2048 * 512;
        const u16* WoTl  = WoT  + (size_t)l * 512 * 1024;
        const u16* WxTl  = WxT  + (size_t)l * 64 * 1024;
        const u16* WdtTl = WdtT + (size_t)l * 1024 * 32;

        // xz = h @ Wi  (4096 x 2048, K=512) -> bf16; async staging, XCD swizzle
        gemm_a<128, 128, 1, u16><<<512, 256, 0, stream>>>(
            abf, WiTl, xzb, 512, 512, 2048, 512);

        // xs = silu(conv(xin) + cb) -> bf16
        conv_silu_kernel<<<4096, 256, 0, stream>>>(
            xzb, cw + (size_t)l * DI * 4, cb + (size_t)l * DI, (ushort4*)xsbf);

        // dbc partials = xs @ Wx  (split-K=8, deterministic stores) + reduce
        gemm_a<128, 64, 0, float><<<dim3(1, 32, 8), 256, 0, stream>>>(
            xsbf, WxTl, pxp, 1024, 1024, 64, 128);
        reduce_dbc<<<256, 256, 0, stream>>>((const float4*)pxp, (float4*)dbc);

        // delta = softplus(dbc[:, :32] @ Wdt + bdt) -> bf16 (single k-iter)
        gemm_dt<<<dim3(8, 32), 256, 0, stream>>>(
            dbc, WdtTl, dltb, bdt + (size_t)l * DI);

        // chunk-parallel selective scan -> y bf16 (into abf)
        scan_pass1<<<BB * NCH * 4, 256, 0, stream>>>(
            dltb, xsbf, dbc, Alog + (size_t)l * DI * DS, Pb, Qb);
        scan_pass2<<<256, 256, 0, stream>>>(Pb, Qb);
        scan_pass3<<<BB * NCH * 4, 256, 0, stream>>>(
            dltb, xsbf, dbc, xzb, Alog + (size_t)l * DI * DS, Dsk + (size_t)l * DI,
            Pb, abf);

        // o = y @ Wo  (4096 x 512, K=1024) -> f32; split-K=2 partials
        gemm_a<64, 128, 0, float><<<dim3(4, 64, 2), 256, 0, stream>>>(
            abf, WoTl, ob, 1024, 1024, 512, 512);

        // h = LN(o0 + o1 + hin); l=0 also writes bf16 h into abf; l=1 -> d_out
        ln_kernel<<<MROWS, 512, 0, stream>>>(
            ob, ob + 2097152, hin, lng + (size_t)l * DM, lnb + (size_t)l * DM,
            (l == 1) ? (float*)d_out : h, abf, l == 0);
    }
}

// Round 11
// 387.938 us; speedup vs baseline: 1.3606x; 1.0147x over previous
//
#include <hip/hip_runtime.h>
#include <cstdint>

// Problem constants
#define BB 4
#define LL 1024
#define DM 512
#define DI 1024
#define DS 16
#define DTR 32
#define NX 64          // DTR + 2*DS
#define MROWS 4096     // B*L
#define CH 32          // scan chunk length
#define NCH 32         // LL / CH

typedef unsigned short u16;
typedef __attribute__((ext_vector_type(8))) short bf16x8;
typedef __attribute__((ext_vector_type(4))) float f32x4;

#if defined(__has_builtin)
#if __has_builtin(__builtin_amdgcn_global_load_lds)
#define HAS_ASYNC 1
#endif
#endif
#ifndef HAS_ASYNC
#define HAS_ASYNC 0
#endif

__device__ __forceinline__ float bf2f(u16 u) {
    union { unsigned int i; float f; } v;
    v.i = ((unsigned int)u) << 16;
    return v.f;
}
__device__ __forceinline__ u16 f2bf(float f) {
    union { float f; unsigned u; } v;
    v.f = f;
    return (u16)((v.u + 0x7fffu + ((v.u >> 16) & 1u)) >> 16);
}
__device__ __forceinline__ unsigned pack_bf16(float a, float b) {
    union { float f; unsigned u; } ua, ub;
    ua.f = a; ub.f = b;
    unsigned ra = (ua.u + 0x7fffu + ((ua.u >> 16) & 1u)) >> 16;
    unsigned rb = (ub.u + 0x7fffu + ((ub.u >> 16) & 1u)) & 0xffff0000u;
    return ra | rb;
}

#if HAS_ASYNC
// async global -> LDS, 16 B per lane. LDS dest = wave-uniform base + lane*16.
__device__ __forceinline__ void gld_lds16(const void* g, void* l) {
    __builtin_amdgcn_global_load_lds(
        (const __attribute__((address_space(1))) void*)(uintptr_t)g,
        (__attribute__((address_space(3))) void*)(unsigned)(uintptr_t)l,
        16, 0, 0);
}
#endif

// ---------------------------------------------------------------------------
// Weight transpose+cast: src[K][N] f32 -> dst[N][K] bf16. z = layer*4 + which.
// z == 8: cast x f32 -> bf16 into abf.
__global__ __launch_bounds__(256) void wtrans(
    const float* __restrict__ Wi, const float* __restrict__ Wo,
    const float* __restrict__ Wx, const float* __restrict__ Wdt,
    u16* __restrict__ WiT, u16* __restrict__ WoT,
    u16* __restrict__ WxT, u16* __restrict__ WdtT,
    const float4* __restrict__ x4, ushort4* __restrict__ xb4)
{
    int z = blockIdx.z;
    if (z == 8) {   // x cast: 524288 float4s over 512 blocks x 256 threads
        int base = (blockIdx.y * 32 + blockIdx.x) * 256 + threadIdx.x;
        for (int i = base; i < 524288; i += 131072) {
            float4 v = x4[i];
            xb4[i] = make_ushort4(f2bf(v.x), f2bf(v.y), f2bf(v.z), f2bf(v.w));
        }
        return;
    }
    int l = z >> 2, w = z & 3;
    int K, N; const float* src; u16* dst;
    if (w == 0)      { K = 512;  N = 2048; src = Wi + (size_t)l * 512 * 2048;  dst = WiT + (size_t)l * 2048 * 512; }
    else if (w == 1) { K = 1024; N = 512;  src = Wo + (size_t)l * 1024 * 512;  dst = WoT + (size_t)l * 512 * 1024; }
    else if (w == 2) { K = 1024; N = 64;   src = Wx + (size_t)l * 1024 * 64;   dst = WxT + (size_t)l * 64 * 1024; }
    else             { K = 32;   N = 1024; src = Wdt + (size_t)l * 32 * 1024;  dst = WdtT + (size_t)l * 1024 * 32; }
    int n0 = blockIdx.x * 64, k0 = blockIdx.y * 64;
    if (n0 >= N || k0 >= K) return;
    __shared__ u16 tile[64][65];
    int tn = threadIdx.x & 63, tr = threadIdx.x >> 6;
    for (int r = tr; r < 64; r += 4) {
        int k = k0 + r;
        if (k < K && n0 + tn < N)
            tile[r][tn] = f2bf(src[(size_t)k * N + n0 + tn]);
    }
    __syncthreads();
    for (int r = tr; r < 64; r += 4) {
        int n = n0 + r, k = k0 + tn;
        if (n < N && k < K)
            dst[(size_t)n * K + k] = tile[tn][r];
    }
}

// ---------------------------------------------------------------------------
// Async-staged MFMA bf16 GEMM, BK=64 (two verified BK=32 sub-tiles per
// barrier pair -- halves barrier-drain count vs round 10). A[M][lda] bf16,
// W[N][ldb] bf16 (pre-transposed), C typed CT. Tile TM x TN, 4 waves (2x2).
// XOR k-group swizzle applied on the GLOBAL address (LDS dest lane-linear);
// per-sub-tile LDS image identical to the verified rounds 4-10 layout.
// Epilogue: LDS-staged wide stores. Split-K via blockIdx.z writes partials
// to distinct C slices. XS: XCD swizzle for in_proj's 16x32 grid.
// Requires kchunk % 64 == 0.
template <int TM, int TN, int XS, typename CT>
__global__ __launch_bounds__(256) void gemm_a(
    const u16* __restrict__ A, const u16* __restrict__ W, CT* __restrict__ C,
    int lda, int ldb, int ldc, int kchunk)
{
    constexpr int NI = TM / 32, NJ = TN / 32;
    constexpr int SLOTS = (TM + TN) / 64;        // per BK=32 sub-tile
    constexpr int STRIDE = (TM + TN) * 64;       // bytes per sub-tile
    constexpr int CSTRIDE = TN * (int)sizeof(CT) + 16;
    constexpr int CBYTES = 32 * CSTRIDE;
    constexpr int SBYTES = 2 * STRIDE;
    constexpr int LBYTES = (CBYTES > SBYTES) ? CBYTES : SBYTES;
    __shared__ char lds[LBYTES];

    const int tid = threadIdx.x;
    const int lane = tid & 63;
    const int wave = tid >> 6;
    const int wm = wave >> 1, wn = wave & 1;
    const int lm = lane & 15, quad = lane >> 4;

    int bx, by;
    if (XS) {   // 16x32 grid; XCD (bid&7) owns an 8x8 block-tile patch
        int bid = blockIdx.x;
        int xcd = bid & 7, idx = bid >> 3;
        by = (xcd & 3) * 8 + (idx & 7);
        bx = (xcd >> 2) * 8 + (idx >> 3);
    } else { bx = blockIdx.x; by = blockIdx.y; }
    const int row0 = by * TM, col0 = bx * TN;
    const int kstart = blockIdx.z * kchunk;
    CT* Cz = C + (size_t)blockIdx.z * (size_t)(gridDim.y * TM) * ldc;

    const int g = tid & 3;
    const u16* gp[SLOTS];
    char* lb[SLOTS];
#pragma unroll
    for (int s = 0; s < SLOTS; ++s) {
        int r = s * 64 + (tid >> 2);
        int gg = (g ^ (r & 3)) * 8;          // xor'd k-group on the global side
        if (r < TM) gp[s] = A + (size_t)(row0 + r) * lda + kstart + gg;
        else        gp[s] = W + (size_t)(col0 + r - TM) * ldb + kstart + gg;
        lb[s] = (char*)lds + (s * 64 + wave * 16) * 64;   // wave-uniform base
    }

    f32x4 acc[NI][NJ];
#pragma unroll
    for (int i = 0; i < NI; ++i)
#pragma unroll
        for (int j = 0; j < NJ; ++j) acc[i][j] = (f32x4){0.f, 0.f, 0.f, 0.f};

    for (int k0 = 0; k0 < kchunk; k0 += 64) {
#if HAS_ASYNC
#pragma unroll
        for (int s = 0; s < SLOTS; ++s) gld_lds16(gp[s], lb[s]);
#pragma unroll
        for (int s = 0; s < SLOTS; ++s) {
            gld_lds16(gp[s] + 32, lb[s] + STRIDE);
            gp[s] += 64;
        }
#else
#pragma unroll
        for (int s = 0; s < SLOTS; ++s) {
            int r = s * 64 + (tid >> 2);
            uint4 v0 = *(const uint4*)gp[s];
            uint4 v1 = *(const uint4*)(gp[s] + 32);
            gp[s] += 64;
            *(uint4*)(lds + r * 64 + (g << 4)) = v0;
            *(uint4*)(lds + STRIDE + r * 64 + (g << 4)) = v1;
        }
#endif
        __syncthreads();   // drains vmcnt (async DMA landed) + barrier

#pragma unroll
        for (int sub = 0; sub < 2; ++sub) {
            const char* base = lds + sub * STRIDE;
            bf16x8 af[NI], bf[NJ];
#pragma unroll
            for (int i = 0; i < NI; ++i) {
                int r = wm * (TM / 2) + i * 16 + lm;
                af[i] = *(const bf16x8*)(base + r * 64 + ((quad ^ (lm & 3)) << 4));
            }
#pragma unroll
            for (int j = 0; j < NJ; ++j) {
                int r = TM + wn * (TN / 2) + j * 16 + lm;
                bf[j] = *(const bf16x8*)(base + r * 64 + ((quad ^ (lm & 3)) << 4));
            }
#pragma unroll
            for (int i = 0; i < NI; ++i)
#pragma unroll
                for (int j = 0; j < NJ; ++j)
                    acc[i][j] = __builtin_amdgcn_mfma_f32_16x16x32_bf16(
                        af[i], bf[j], acc[i][j], 0, 0, 0);
        }
        __syncthreads();   // frag reads done before next stage overwrites
    }

    // LDS-staged wide-store epilogue
#pragma unroll
    for (int i = 0; i < NI; ++i) {
        __syncthreads();
#pragma unroll
        for (int j = 0; j < NJ; ++j) {
#pragma unroll
            for (int r = 0; r < 4; ++r) {
                int lr = wm * 16 + quad * 4 + r;
                int lc = wn * (TN / 2) + j * 16 + lm;
                float val = acc[i][j][r];
                if (sizeof(CT) == 2)
                    *(u16*)(lds + lr * CSTRIDE + lc * 2) = f2bf(val);
                else
                    *(float*)(lds + lr * CSTRIDE + lc * 4) = val;
            }
        }
        __syncthreads();
        constexpr int TPR = TN * (int)sizeof(CT) / 16;
        int seg = tid % TPR;
        for (int rr = tid / TPR; rr < 32; rr += 256 / TPR) {
            int gr = row0 + (rr >> 4) * (TM / 2) + i * 16 + (rr & 15);
            *(uint4*)((char*)(Cz + (size_t)gr * ldc + col0) + seg * 16) =
                *(const uint4*)(lds + rr * CSTRIDE + seg * 16);
        }
    }
}

// ---------------------------------------------------------------------------
// dt_proj fused with the x_proj split-K reduction: A = sum_z pxp[z] computed
// inline during staging (z-ascending order == old reduce_dbc, bit-identical);
// bx==0 blocks side-write dbc f32 for the scan. delta = softplus(A[:, :32] @
// Wdt + bdt) -> bf16. K=32 -> single MFMA k-iter. TM=TN=128.
__global__ __launch_bounds__(256) void gemm_dt(
    const float* __restrict__ pxp, const u16* __restrict__ W,
    u16* __restrict__ C, float* __restrict__ dbc, const float* __restrict__ bias)
{
    __shared__ char lds[16384];
    const int tid = threadIdx.x;
    const int lane = tid & 63, wave = tid >> 6;
    const int wm = wave >> 1, wn = wave & 1;
    const int lm = lane & 15, quad = lane >> 4;
    const int row0 = blockIdx.y * 128, col0 = blockIdx.x * 128;
    const int g = tid & 3;

#pragma unroll
    for (int s = 0; s < 4; ++s) {
        int r = s * 64 + (tid >> 2);
        uint4 w;
        if (r < 128) {
            size_t off = (size_t)(row0 + r) * NX + g * 8;
            float4 a0 = make_float4(0.f, 0.f, 0.f, 0.f);
            float4 a1 = make_float4(0.f, 0.f, 0.f, 0.f);
#pragma unroll
            for (int z = 0; z < 8; ++z) {
                const float* p = pxp + (size_t)z * 262144 + off;
                float4 v0 = *(const float4*)p, v1 = *(const float4*)(p + 4);
                a0.x += v0.x; a0.y += v0.y; a0.z += v0.z; a0.w += v0.w;
                a1.x += v1.x; a1.y += v1.y; a1.z += v1.z; a1.w += v1.w;
            }
            if (blockIdx.x == 0) {
                *(float4*)(dbc + off) = a0;
                *(float4*)(dbc + off + 4) = a1;
            }
            w.x = pack_bf16(a0.x, a0.y); w.y = pack_bf16(a0.z, a0.w);
            w.z = pack_bf16(a1.x, a1.y); w.w = pack_bf16(a1.z, a1.w);
        } else {
            w = *(const uint4*)(W + (size_t)(col0 + r - 128) * 32 + g * 8);
        }
        *(uint4*)(lds + r * 64 + (((g ^ (r & 3))) << 4)) = w;
    }
    __syncthreads();

    bf16x8 af[4], bf[4];
#pragma unroll
    for (int i = 0; i < 4; ++i) {
        int r = wm * 64 + i * 16 + lm;
        af[i] = *(const bf16x8*)(lds + r * 64 + ((quad ^ (lm & 3)) << 4));
    }
#pragma unroll
    for (int j = 0; j < 4; ++j) {
        int r = 128 + wn * 64 + j * 16 + lm;
        bf[j] = *(const bf16x8*)(lds + r * 64 + ((quad ^ (lm & 3)) << 4));
    }
    f32x4 acc[4][4];
#pragma unroll
    for (int i = 0; i < 4; ++i)
#pragma unroll
        for (int j = 0; j < 4; ++j)
            acc[i][j] = __builtin_amdgcn_mfma_f32_16x16x32_bf16(
                af[i], bf[j], (f32x4){0.f, 0.f, 0.f, 0.f}, 0, 0, 0);

    constexpr int CSTRIDE = 128 * 2 + 16;
#pragma unroll
    for (int i = 0; i < 4; ++i) {
        __syncthreads();
#pragma unroll
        for (int j = 0; j < 4; ++j) {
#pragma unroll
            for (int r = 0; r < 4; ++r) {
                int lr = wm * 16 + quad * 4 + r;
                int lc = wn * 64 + j * 16 + lm;
                float val = acc[i][j][r] + bias[col0 + lc];
                val = fmaxf(val, 0.f) + log1pf(__expf(-fabsf(val)));
                *(u16*)(lds + lr * CSTRIDE + lc * 2) = f2bf(val);
            }
        }
        __syncthreads();
        int seg = tid & 15;
        for (int rr = tid >> 4; rr < 32; rr += 16) {
            int gr = row0 + (rr >> 4) * 64 + i * 16 + (rr & 15);
            *(uint4*)((char*)(C + (size_t)gr * DI + col0) + seg * 16) =
                *(const uint4*)(lds + rr * CSTRIDE + seg * 16);
        }
    }
}

// ---------------------------------------------------------------------------
// depthwise causal conv (kernel 4) + bias + SiLU; bf16 in (xz), bf16 out (xs)
__global__ void conv_silu_kernel(const u16* __restrict__ xz,
                                 const float* __restrict__ cw, const float* __restrict__ cb,
                                 ushort4* __restrict__ xs)
{
    int i = blockIdx.x * 256 + threadIdx.x;   // 0 .. 1M-1 (d-quads)
    int d = (i & 255) * 4;
    int bt = i >> 8;
    int t = bt & (LL - 1);
    float a0 = cb[d], a1 = cb[d + 1], a2 = cb[d + 2], a3 = cb[d + 3];
    float4 w0 = *(const float4*)(cw + (size_t)d * 4);
    float4 w1 = *(const float4*)(cw + (size_t)(d + 1) * 4);
    float4 w2 = *(const float4*)(cw + (size_t)(d + 2) * 4);
    float4 w3 = *(const float4*)(cw + (size_t)(d + 3) * 4);
    const float* wp0 = (const float*)&w0;
    const float* wp1 = (const float*)&w1;
    const float* wp2 = (const float*)&w2;
    const float* wp3 = (const float*)&w3;
#pragma unroll
    for (int k = 0; k < 4; ++k) {
        int tt = t - 3 + k;
        if (tt >= 0) {
            ushort4 xv = *(const ushort4*)(xz + (size_t)(bt - 3 + k) * 2048 + d);
            a0 = fmaf(bf2f(xv.x), wp0[k], a0);
            a1 = fmaf(bf2f(xv.y), wp1[k], a1);
            a2 = fmaf(bf2f(xv.z), wp2[k], a2);
            a3 = fmaf(bf2f(xv.w), wp3[k], a3);
        }
    }
    xs[i] = make_ushort4(
        f2bf(a0 / (1.f + __expf(-a0))), f2bf(a1 / (1.f + __expf(-a1))),
        f2bf(a2 / (1.f + __expf(-a2))), f2bf(a3 / (1.f + __expf(-a3))));
}

// ---------------------------------------------------------------------------
// Chunk-parallel scan, register-state (one thread = all 16 states of (b,chunk,d))
__global__ __launch_bounds__(256) void scan_pass1(
    const u16* __restrict__ delta, const u16* __restrict__ xs,
    const float* __restrict__ dbc, const float* __restrict__ A_log,
    float* __restrict__ P, float* __restrict__ Q)
{
    const int dgrp = blockIdx.x & 3;
    const int chunk = (blockIdx.x >> 2) & (NCH - 1);
    const int b = blockIdx.x >> 7;
    const int d = dgrp * 256 + threadIdx.x;
    const int t0 = b * LL + chunk * CH;

    __shared__ float sB[CH][DS];
    {
        int i = threadIdx.x;
        int row = i >> 3, col = (i & 7) * 2;
        float2 v = *(const float2*)(dbc + (size_t)(t0 + row) * NX + DTR + col);
        sB[row][col] = v.x; sB[row][col + 1] = v.y;
    }
    float An[DS];
#pragma unroll
    for (int n = 0; n < DS; ++n) An[n] = -__expf(A_log[d * DS + n]);
    __syncthreads();

    float Pv[DS], h[DS];
#pragma unroll
    for (int n = 0; n < DS; ++n) { Pv[n] = 1.f; h[n] = 0.f; }

    const u16* dp = delta + (size_t)t0 * DI + d;
    const u16* xp = xs + (size_t)t0 * DI + d;
#pragma unroll 4
    for (int t = 0; t < CH; ++t) {
        float dlt = bf2f(dp[t * DI]);
        float du = dlt * bf2f(xp[t * DI]);
#pragma unroll
        for (int n = 0; n < DS; ++n) {
            float dA = __expf(dlt * An[n]);
            Pv[n] *= dA;
            h[n] = fmaf(dA, h[n], du * sB[t][n]);
        }
    }
    size_t base = ((size_t)(b * NCH + chunk) * DI + d) * DS;
    float4* Pp = (float4*)(P + base);
    float4* Qp = (float4*)(Q + base);
#pragma unroll
    for (int g = 0; g < 4; ++g) {
        Pp[g] = make_float4(Pv[g * 4], Pv[g * 4 + 1], Pv[g * 4 + 2], Pv[g * 4 + 3]);
        Qp[g] = make_float4(h[g * 4], h[g * 4 + 1], h[g * 4 + 2], h[g * 4 + 3]);
    }
}

__global__ __launch_bounds__(256) void scan_pass2(float* __restrict__ P,
                                                  const float* __restrict__ Q)
{
    int tid = blockIdx.x * 256 + threadIdx.x;
    int n = tid & 15;
    int d = (tid >> 4) & (DI - 1);
    int b = tid >> 14;
    float carry = 0.f;
    for (int c = 0; c < NCH; ++c) {
        size_t i = ((size_t)(b * NCH + c) * DI + d) * DS + n;
        float Pv = P[i], Qv = Q[i];
        P[i] = carry;
        carry = fmaf(Pv, carry, Qv);
    }
}

// pass3: re-run from H_in; y = sum_n h_n C_n + D-skip, silu(z) gate -> y bf16
__global__ __launch_bounds__(256) void scan_pass3(
    const u16* __restrict__ delta, const u16* __restrict__ xs,
    const float* __restrict__ dbc, const u16* __restrict__ xz,
    const float* __restrict__ A_log, const float* __restrict__ Dsk,
    const float* __restrict__ Hin, u16* __restrict__ yb)
{
    const int dgrp = blockIdx.x & 3;
    const int chunk = (blockIdx.x >> 2) & (NCH - 1);
    const int b = blockIdx.x >> 7;
    const int d = dgrp * 256 + threadIdx.x;
    const int t0 = b * LL + chunk * CH;

    __shared__ float sBC[CH][32];   // cols 0..15 = B, 16..31 = C
    {
        int i = threadIdx.x;
        int row = i >> 3, col = (i & 7) * 4;
        float4 v = *(const float4*)(dbc + (size_t)(t0 + row) * NX + DTR + col);
        *(float4*)&sBC[row][col] = v;
    }
    float An[DS];
#pragma unroll
    for (int n = 0; n < DS; ++n) An[n] = -__expf(A_log[d * DS + n]);
    const float Dd = Dsk[d];

    float h[DS];
    {
        size_t base = ((size_t)(b * NCH + chunk) * DI + d) * DS;
        const float4* Hp = (const float4*)(Hin + base);
#pragma unroll
        for (int g = 0; g < 4; ++g) {
            float4 v = Hp[g];
            h[g * 4] = v.x; h[g * 4 + 1] = v.y; h[g * 4 + 2] = v.z; h[g * 4 + 3] = v.w;
        }
    }
    __syncthreads();

    const u16* dp = delta + (size_t)t0 * DI + d;
    const u16* xp = xs + (size_t)t0 * DI + d;
    const u16* zp = xz + (size_t)t0 * 2048 + DI + d;
    u16* yp = yb + (size_t)t0 * DI + d;

#pragma unroll 4
    for (int t = 0; t < CH; ++t) {
        float dlt = bf2f(dp[t * DI]);
        float xv  = bf2f(xp[t * DI]);
        float zv  = bf2f(zp[t * 2048]);
        float du = dlt * xv;
        float y = 0.f;
#pragma unroll
        for (int n = 0; n < DS; ++n) {
            float dA = __expf(dlt * An[n]);
            h[n] = fmaf(dA, h[n], du * sBC[t][n]);
            y = fmaf(h[n], sBC[t][DS + n], y);
        }
        y += xv * Dd;
        float sz = zv / (1.f + __expf(-zv));
        yp[t * DI] = f2bf(y * sz);
    }
}

// ---------------------------------------------------------------------------
// residual add + LayerNorm; sums four out_proj split-K partials.
// writes f32 hout; optionally bf16 copy (next GEMM A)
__global__ __launch_bounds__(512) void ln_kernel(
    const float* __restrict__ ob, const float* __restrict__ hprev,
    const float* __restrict__ g, const float* __restrict__ bta,
    float* __restrict__ hout, u16* __restrict__ hbf, int wb)
{
    int row = blockIdx.x, c = threadIdx.x;
    size_t off = (size_t)row * DM + c;
    float v = hprev[off];
#pragma unroll
    for (int z = 0; z < 4; ++z) v += ob[(size_t)z * 2097152 + off];
    float s1 = v, s2 = v * v;
#pragma unroll
    for (int m = 32; m >= 1; m >>= 1) {
        s1 += __shfl_xor(s1, m);
        s2 += __shfl_xor(s2, m);
    }
    __shared__ float r1[8], r2[8];
    __shared__ float stats[2];
    int w = c >> 6;
    if ((c & 63) == 0) { r1[w] = s1; r2[w] = s2; }
    __syncthreads();
    if (c == 0) {
        float a = 0.f, q = 0.f;
        for (int i = 0; i < 8; ++i) { a += r1[i]; q += r2[i]; }
        float mean = a / (float)DM;
        float var = q / (float)DM - mean * mean;
        stats[0] = mean;
        stats[1] = rsqrtf(var + 1e-5f);
    }
    __syncthreads();
    float res = (v - stats[0]) * stats[1] * g[c] + bta[c];
    hout[off] = res;
    if (wb) hbf[off] = f2bf(res);
}

// ---------------------------------------------------------------------------
extern "C" void kernel_launch(void* const* d_in, const int* in_sizes, int n_in,
                              void* d_out, int out_size, void* d_ws, size_t ws_size,
                              hipStream_t stream)
{
    const float* x    = (const float*)d_in[0];
    const float* Wi   = (const float*)d_in[1];
    const float* cw   = (const float*)d_in[2];
    const float* cb   = (const float*)d_in[3];
    const float* Wx   = (const float*)d_in[4];
    const float* Wdt  = (const float*)d_in[5];
    const float* bdt  = (const float*)d_in[6];
    const float* Alog = (const float*)d_in[7];
    const float* Dsk  = (const float*)d_in[8];
    const float* Wo   = (const float*)d_in[9];
    const float* lng  = (const float*)d_in[10];
    const float* lnb  = (const float*)d_in[11];

    float* fw   = (float*)d_ws;
    float* h    = fw;                      // 2M f32
    float* ob   = h + 2097152;             // 4 x 2M f32 (out_proj split-K partials)
    float* dbc  = ob + 8388608;            // 256K f32
    float* pxp  = dbc + 262144;            // 2M f32 (8 x 4096 x 64 partials)
    float* Pb   = pxp + 2097152;           // 2M f32
    float* Qb   = Pb + 2097152;            // 2M f32
    u16* xzb    = (u16*)(Qb + 2097152);    // 8M u16 (4096 x 2048)
    u16* xsbf   = xzb + 8388608;           // 4M u16
    u16* abf    = xsbf + 4194304;          // 4M u16 (x/h bf16, then y bf16)
    u16* dltb   = abf + 4194304;           // 4M u16
    u16* WiT    = dltb + 4194304;          // 2 x 1M u16
    u16* WoT    = WiT + 2097152;           // 2 x 512K u16
    u16* WxT    = WoT + 1048576;           // 2 x 64K u16
    u16* WdtT   = WxT + 131072;            // 2 x 32K u16

    // one-time: all weights -> [N][K] bf16; z=8 casts x -> bf16 (abf)
    wtrans<<<dim3(32, 16, 9), 256, 0, stream>>>(
        Wi, Wo, Wx, Wdt, WiT, WoT, WxT, WdtT, (const float4*)x, (ushort4*)abf);

    for (int l = 0; l < 2; ++l) {
        const float* hin = (l == 0) ? x : h;
        const u16* WiTl  = WiT  + (size_t)l * 2048 * 512;
        const u16* WoTl  = WoT  + (size_t)l * 512 * 1024;
        const u16* WxTl  = WxT  + (size_t)l * 64 * 1024;
        const u16* WdtTl = WdtT + (size_t)l * 1024 * 32;

        // xz = h @ Wi  (4096 x 2048, K=512) -> bf16; async BK=64, XCD swizzle
        gemm_a<128, 128, 1, u16><<<512, 256, 0, stream>>>(
            abf, WiTl, xzb, 512, 512, 2048, 512);

        // xs = silu(conv(xin) + cb) -> bf16
        conv_silu_kernel<<<4096, 256, 0, stream>>>(
            xzb, cw + (size_t)l * DI * 4, cb + (size_t)l * DI, (ushort4*)xsbf);

        // dbc partials = xs @ Wx  (split-K=8, deterministic stores)
        gemm_a<128, 64, 0, float><<<dim3(1, 32, 8), 256, 0, stream>>>(
            xsbf, WxTl, pxp, 1024, 1024, 64, 128);

        // delta = softplus(sum_z(pxp)[:, :32] @ Wdt + bdt) -> bf16;
        // also writes dbc f32 (bx==0 blocks)
        gemm_dt<<<dim3(8, 32), 256, 0, stream>>>(
            pxp, WdtTl, dltb, dbc, bdt + (size_t)l * DI);

        // chunk-parallel selective scan -> y bf16 (into abf)
        scan_pass1<<<BB * NCH * 4, 256, 0, stream>>>(
            dltb, xsbf, dbc, Alog + (size_t)l * DI * DS, Pb, Qb);
        scan_pass2<<<256, 256, 0, stream>>>(Pb, Qb);
        scan_pass3<<<BB * NCH * 4, 256, 0, stream>>>(
            dltb, xsbf, dbc, xzb, Alog + (size_t)l * DI * DS, Dsk + (size_t)l * DI,
            Pb, abf);

        // o = y @ Wo  (4096 x 512, K=1024) -> f32; split-K=4 partials
        gemm_a<64, 128, 0, float><<<dim3(4, 64, 4), 256, 0, stream>>>(
            abf, WoTl, ob, 1024, 1024, 512, 256);

        // h = LN(sum_z o_z + hin); l=0 writes bf16 h into abf; l=1 -> d_out
        ln_kernel<<<MROWS, 512, 0, stream>>>(
            ob, hin, lng + (size_t)l * DM, lnb + (size_t)l * DM,
            (l == 1) ? (float*)d_out : h, abf, l == 0);
    }
}